// Round 3
// baseline (2882.201 us; speedup 1.0000x reference)
//
#include <hip/hip_runtime.h>

#define N_LB   4096
#define N_ULB  6144
#define N_TOT  16384
#define D      128
#define C      100
#define CP     128

// d_out element offsets (f32 elements, reference return order)
#define OFF_ANCHOR 0
#define OFF_POS    786432
#define OFF_LBF    1572864
#define OFF_OH     2097152
#define OFF_OUTLB  2506752   // out_lb / out_ulb_1 / out_ulb_2 are row-contiguous
#define OFF_SCAL   4145152

// ---------------------------------------------------------------------------
// prep_feats: L2-normalize rows into ws F[16384][128]; exact f32 passthrough
// of the raw features to d_out. One 64-thread wave per row.
// ---------------------------------------------------------------------------
__global__ void prep_feats(const float* __restrict__ anchor,
                           const float* __restrict__ positive,
                           const float* __restrict__ lbf,
                           float* __restrict__ F,
                           float* __restrict__ out)
{
    const int r = blockIdx.x;
    const int t = threadIdx.x;   // 0..63
    const float* src; int rr, ptbase;
    if (r < N_LB)              { src = lbf;      rr = r;                ptbase = OFF_LBF; }
    else if (r < N_LB + N_ULB) { src = anchor;   rr = r - N_LB;         ptbase = OFF_ANCHOR; }
    else                       { src = positive; rr = r - N_LB - N_ULB; ptbase = OFF_POS; }
    float2 x = *(const float2*)&src[rr * D + 2 * t];
    float ss = x.x * x.x + x.y * x.y;
    #pragma unroll
    for (int m = 32; m; m >>= 1) ss += __shfl_xor(ss, m);
    float inv = 1.0f / fmaxf(sqrtf(ss), 1e-12f);
    F[r * D + 2 * t]     = x.x * inv;
    F[r * D + 2 * t + 1] = x.y * inv;
    *(float2*)&out[ptbase + rr * D + 2 * t] = x;   // exact bit copy
}

// ---------------------------------------------------------------------------
// prep_logits: build padded L[16384][128] (cols 0..99 = logits, col 100 = 1.0
// as the folded softmax denominator, rest 0); pred_before via exact
// first-occurrence argmax on the raw f32 values (matches jnp/np.argmax).
// ---------------------------------------------------------------------------
__global__ void prep_logits(const float* __restrict__ l_lb,
                            const float* __restrict__ l_u1,
                            const float* __restrict__ l_u2,
                            float* __restrict__ L,
                            int* __restrict__ predB)
{
    const int r = blockIdx.x;
    const int t = threadIdx.x;   // 0..63
    const float* src; int rr;
    if (r < N_LB)              { src = l_lb; rr = r; }
    else if (r < N_LB + N_ULB) { src = l_u1; rr = r - N_LB; }
    else                       { src = l_u2; rr = r - N_LB - N_ULB; }
    float v0 = src[rr * C + t];                    // t < 64 < 100 always valid
    const int c1 = t + 64;
    float v1 = (c1 < C) ? src[rr * C + c1] : 0.0f;
    L[r * CP + t]  = v0;
    L[r * CP + c1] = (c1 < C) ? v1 : ((c1 == C) ? 1.0f : 0.0f);
    float bv = v0; int bi = t;
    if (c1 < C && v1 > bv) { bv = v1; bi = c1; }
    #pragma unroll
    for (int m = 32; m; m >>= 1) {
        float ov = __shfl_xor(bv, m);
        int   oi = __shfl_xor(bi, m);
        if (ov > bv || (ov == bv && oi < bi)) { bv = ov; bi = oi; }
    }
    if (t == 0) predB[r] = bi;
}

// ---------------------------------------------------------------------------
__global__ void copy_oh(const float4* __restrict__ oh, float4* __restrict__ out)
{
    // lb_one_hot passthrough: 409600 f32 = 102400 float4, exact bit copy
    for (int i = blockIdx.x * blockDim.x + threadIdx.x; i < N_LB * C / 4;
         i += gridDim.x * blockDim.x)
        out[i] = oh[i];
}

// ---------------------------------------------------------------------------
// attn: flash-style fused sim->softmax->PV with FIXED shift c = 1/tau = 10
// (row max of sim is the diagonal since rows are L2-normalized, cos<=1), so
// no online max / rescaling: acc += sum_j e^{10 dot - 10} * L[j], and the
// denominator rides along as padded class 100 (=1.0).
// 256 blocks x 256 threads, BM=64 rows/block, BN=64 keys/chunk.
// sA/sB: [64][128] f32, XOR-swizzled so 4-row-strided b128 reads spread banks.
// ---------------------------------------------------------------------------
__device__ __forceinline__ float4 lds_rd4(const float* s, int r, int k) {
    return *(const float4*)&s[r * 128 + (k ^ (((r >> 2) & 7) << 2))];
}
__device__ __forceinline__ void lds_wr4(float* s, int r, int k, float4 v) {
    *(float4*)&s[r * 128 + (k ^ (((r >> 2) & 7) << 2))] = v;
}

__launch_bounds__(256, 1)
__global__ void attn_kernel(const float* __restrict__ F, const float* __restrict__ L,
                            float* __restrict__ out)
{
    __shared__ __align__(16) float sA[64 * 128];   // Q rows (swizzled)
    __shared__ __align__(16) float sB[64 * 128];   // key rows (swizzled)
    __shared__ __align__(16) float sP[64 * 68];    // P^T [key][row], pad 68
    __shared__ __align__(16) float sL[64 * 132];   // L tile [key][class], pad 132
    __shared__ float sInv[64];

    const int tid = threadIdx.x;
    const int r0  = blockIdx.x * 64;
    const int rg  = tid & 15;    // row group (4 rows)
    const int cg  = tid >> 4;    // S: col group (4 keys) / PV: class group (8)

    #pragma unroll
    for (int it = 0; it < 8; ++it) {               // stage A tile once
        int w4 = tid + it * 256;
        int r = w4 >> 5, k4 = (w4 & 31) << 2;
        lds_wr4(sA, r, k4, *(const float4*)&F[(r0 + r) * D + k4]);
    }

    float o[4][8];
    #pragma unroll
    for (int i = 0; i < 4; ++i)
        #pragma unroll
        for (int j = 0; j < 8; ++j) o[i][j] = 0.0f;

    for (int ch = 0; ch < 256; ++ch) {
        const int c0 = ch * 64;
        __syncthreads();                           // prev PV done with sL/sP
        #pragma unroll
        for (int it = 0; it < 8; ++it) {           // stage keys
            int w4 = tid + it * 256;
            int r = w4 >> 5, k4 = (w4 & 31) << 2;
            lds_wr4(sB, r, k4, *(const float4*)&F[(c0 + r) * D + k4]);
        }
        #pragma unroll
        for (int it = 0; it < 8; ++it) {           // stage logits tile (linear+pad)
            int w4 = tid + it * 256;
            int r = w4 >> 5, k4 = (w4 & 31) << 2;
            *(float4*)&sL[r * 132 + k4] = *(const float4*)&L[(c0 + r) * CP + k4];
        }
        __syncthreads();

        // ---- S = Q . K^T  (4x4 micro, k-vectorized) ----
        float s[4][4];
        #pragma unroll
        for (int i = 0; i < 4; ++i)
            #pragma unroll
            for (int j = 0; j < 4; ++j) s[i][j] = 0.0f;

        #pragma unroll 4
        for (int k4 = 0; k4 < D; k4 += 4) {
            float4 a[4], b[4];
            #pragma unroll
            for (int i = 0; i < 4; ++i) a[i] = lds_rd4(sA, rg * 4 + i, k4);
            #pragma unroll
            for (int j = 0; j < 4; ++j) b[j] = lds_rd4(sB, cg * 4 + j, k4);
            #pragma unroll
            for (int i = 0; i < 4; ++i)
                #pragma unroll
                for (int j = 0; j < 4; ++j) {
                    s[i][j] = fmaf(a[i].x, b[j].x, s[i][j]);
                    s[i][j] = fmaf(a[i].y, b[j].y, s[i][j]);
                    s[i][j] = fmaf(a[i].z, b[j].z, s[i][j]);
                    s[i][j] = fmaf(a[i].w, b[j].w, s[i][j]);
                }
        }
        // ---- P = exp(10*sim - 10), store P^T ----
        #pragma unroll
        for (int j = 0; j < 4; ++j)
            #pragma unroll
            for (int i = 0; i < 4; ++i)
                sP[(cg * 4 + j) * 68 + rg * 4 + i] = __expf(10.0f * s[i][j] - 10.0f);
        __syncthreads();

        // ---- PV: acc[4 rows][8 classes] += P^T . Ltile ----
        #pragma unroll 4
        for (int kk = 0; kk < 64; ++kk) {
            float4 pv = *(const float4*)&sP[kk * 68 + rg * 4];
            float4 l0 = *(const float4*)&sL[kk * 132 + cg * 8];
            float4 l1 = *(const float4*)&sL[kk * 132 + cg * 8 + 4];
            #pragma unroll
            for (int i = 0; i < 4; ++i) {
                float p = (i == 0) ? pv.x : (i == 1) ? pv.y : (i == 2) ? pv.z : pv.w;
                o[i][0] = fmaf(p, l0.x, o[i][0]);
                o[i][1] = fmaf(p, l0.y, o[i][1]);
                o[i][2] = fmaf(p, l0.z, o[i][2]);
                o[i][3] = fmaf(p, l0.w, o[i][3]);
                o[i][4] = fmaf(p, l1.x, o[i][4]);
                o[i][5] = fmaf(p, l1.y, o[i][5]);
                o[i][6] = fmaf(p, l1.z, o[i][6]);
                o[i][7] = fmaf(p, l1.w, o[i][7]);
            }
        }
    }

    // class 100 (the folded denominator) lives in class-group 12, slot 4
    if (cg == 12) {
        #pragma unroll
        for (int i = 0; i < 4; ++i) sInv[rg * 4 + i] = 1.0f / o[i][4];
    }
    __syncthreads();

    // logits_after rows are contiguous in d_out starting at OFF_OUTLB
    #pragma unroll
    for (int i = 0; i < 4; ++i) {
        const int row = r0 + rg * 4 + i;
        const float inv = sInv[rg * 4 + i];
        #pragma unroll
        for (int j = 0; j < 8; ++j) {
            int cls = cg * 8 + j;
            if (cls < C)
                out[OFF_OUTLB + row * C + cls] = o[i][j] * inv;
        }
    }
}

// ---------------------------------------------------------------------------
__global__ void argmax_after(const float* __restrict__ LA, int* __restrict__ predA)
{
    const int lane = threadIdx.x & 63;
    const int row  = blockIdx.x * 4 + (threadIdx.x >> 6);
    float bv = LA[row * C + lane]; int bi = lane;
    const int c1 = lane + 64;
    if (c1 < C) { float v1 = LA[row * C + c1]; if (v1 > bv) { bv = v1; bi = c1; } }
    #pragma unroll
    for (int m = 32; m; m >>= 1) {
        float ov = __shfl_xor(bv, m);
        int   oi = __shfl_xor(bi, m);
        if (ov > bv || (ov == bv && oi < bi)) { bv = ov; bi = oi; }
    }
    if (lane == 0) predA[row] = bi;
}

// ---------------------------------------------------------------------------
// finalize: diff is identically 0 (softmax over a singleton axis = 1), so
// argmax and argmin of where(changed, 0, +-inf) both select the FIRST row
// where pred_before != pred_after; fallback 0 if none changed.
// ---------------------------------------------------------------------------
__global__ void finalize(const int* __restrict__ predA, const int* __restrict__ predB,
                         float* __restrict__ out)
{
    __shared__ int sm[256];
    const int t = threadIdx.x;
    int local = N_TOT;
    for (int r = t; r < N_TOT; r += 256)
        if (predA[r] != predB[r] && r < local) local = r;
    sm[t] = local;
    __syncthreads();
    for (int s = 128; s; s >>= 1) {
        if (t < s) sm[t] = min(sm[t], sm[t + s]);
        __syncthreads();
    }
    if (t == 0) {
        int first = (sm[0] == N_TOT) ? 0 : sm[0];
        out[OFF_SCAL + 0] = (float)first;           // max_diff_idx
        out[OFF_SCAL + 1] = (float)first;           // min_diff_idx
        out[OFF_SCAL + 2] = (float)predB[first];    // pred_max_diff_bf
        out[OFF_SCAL + 3] = (float)predA[first];    // pred_max_diff_af
        out[OFF_SCAL + 4] = (float)predB[first];    // pred_min_diff_bf
        out[OFF_SCAL + 5] = (float)predA[first];    // pred_min_diff_af
    }
}

// ---------------------------------------------------------------------------
extern "C" void kernel_launch(void* const* d_in, const int* in_sizes, int n_in,
                              void* d_out, int out_size, void* d_ws, size_t ws_size,
                              hipStream_t stream)
{
    const float* anchor   = (const float*)d_in[0];
    const float* positive = (const float*)d_in[1];
    const float* lbf      = (const float*)d_in[2];
    const float* oh       = (const float*)d_in[3];
    const float* l_lb     = (const float*)d_in[4];
    const float* l_u1     = (const float*)d_in[5];
    const float* l_u2     = (const float*)d_in[6];
    float* out = (float*)d_out;

    float* F  = (float*)d_ws;                 //  8 MB
    float* L  = F + (size_t)N_TOT * CP;       //  8 MB
    int* predB = (int*)(L + (size_t)N_TOT * CP);
    int* predA = predB + N_TOT;

    prep_feats <<<N_TOT, 64, 0, stream>>>(anchor, positive, lbf, F, out);
    prep_logits<<<N_TOT, 64, 0, stream>>>(l_lb, l_u1, l_u2, L, predB);
    copy_oh    <<<200, 256, 0, stream>>>((const float4*)oh, (float4*)&out[OFF_OH]);
    attn_kernel<<<256, 256, 0, stream>>>(F, L, out);
    argmax_after<<<N_TOT / 4, 256, 0, stream>>>(&out[OFF_OUTLB], predA);
    finalize   <<<1, 256, 0, stream>>>(predA, predB, out);
}

// Round 4
// 916.904 us; speedup vs baseline: 3.1434x; 3.1434x over previous
//
#include <hip/hip_runtime.h>
#include <hip/hip_bf16.h>

typedef unsigned short u16;
typedef unsigned int u32;
typedef __attribute__((ext_vector_type(8))) short short8;
typedef __attribute__((ext_vector_type(4))) float f32x4;

#define N_LB   4096
#define N_ULB  6144
#define N_TOT  16384
#define D      128
#define C      100
#define CT     104   // classes stored in LT (100 logits + denom@100 + 3 zero)

// d_out element offsets (f32 elements, reference return order)
#define OFF_ANCHOR 0
#define OFF_POS    786432
#define OFF_LBF    1572864
#define OFF_OH     2097152
#define OFF_OUTLB  2506752   // out_lb / out_ulb_1 / out_ulb_2 row-contiguous
#define OFF_SCAL   4145152

__device__ __forceinline__ void split_bf16(float x, u16& hi, u16& lo) {
    __hip_bfloat16 h = __float2bfloat16(x);
    float r = x - __bfloat162float(h);
    __hip_bfloat16 l = __float2bfloat16(r);
    hi = __bfloat16_as_ushort(h);
    lo = __bfloat16_as_ushort(l);
}

// ---------------------------------------------------------------------------
// prep_feats: L2-normalize rows; split to bf16 hi/lo planes in ws
// F2[16384][256] u16 (row = [hi 0..127 | lo 128..255]); exact f32 passthrough.
// ---------------------------------------------------------------------------
__global__ void prep_feats(const float* __restrict__ anchor,
                           const float* __restrict__ positive,
                           const float* __restrict__ lbf,
                           u16* __restrict__ F2,
                           float* __restrict__ out)
{
    const int r = blockIdx.x;
    const int t = threadIdx.x;   // 0..63
    const float* src; int rr, ptbase;
    if (r < N_LB)              { src = lbf;      rr = r;                ptbase = OFF_LBF; }
    else if (r < N_LB + N_ULB) { src = anchor;   rr = r - N_LB;         ptbase = OFF_ANCHOR; }
    else                       { src = positive; rr = r - N_LB - N_ULB; ptbase = OFF_POS; }
    float2 x = *(const float2*)&src[rr * D + 2 * t];
    float ss = x.x * x.x + x.y * x.y;
    #pragma unroll
    for (int m = 32; m; m >>= 1) ss += __shfl_xor(ss, m);
    float inv = 1.0f / fmaxf(sqrtf(ss), 1e-12f);
    float y0 = x.x * inv, y1 = x.y * inv;
    u16 h0, l0, h1, l1;
    split_bf16(y0, h0, l0);
    split_bf16(y1, h1, l1);
    *(u32*)&F2[r * 256 + 2 * t]       = (u32)h0 | ((u32)h1 << 16);
    *(u32*)&F2[r * 256 + 128 + 2 * t] = (u32)l0 | ((u32)l1 << 16);
    *(float2*)&out[ptbase + rr * D + 2 * t] = x;   // exact bit copy
}

// ---------------------------------------------------------------------------
// prep_logits: build transposed split-bf16 LT[pl][cls][key]: cls 0..99 =
// logits, cls 100 = 1.0 (folded softmax denominator), 101..103 = 0.
// pred_before via exact first-occurrence argmax.
// ---------------------------------------------------------------------------
__global__ void prep_logits(const float* __restrict__ l_lb,
                            const float* __restrict__ l_u1,
                            const float* __restrict__ l_u2,
                            u16* __restrict__ LT,
                            int* __restrict__ predB)
{
    const int r = blockIdx.x;
    const int t = threadIdx.x;   // 0..63
    const float* src; int rr;
    if (r < N_LB)              { src = l_lb; rr = r; }
    else if (r < N_LB + N_ULB) { src = l_u1; rr = r - N_LB; }
    else                       { src = l_u2; rr = r - N_LB - N_ULB; }
    float v0 = src[rr * C + t];
    const int c1 = t + 64;
    float v1 = (c1 < C) ? src[rr * C + c1] : 0.0f;
    u16 h, l;
    split_bf16(v0, h, l);
    LT[(size_t)(0 * CT + t) * N_TOT + r] = h;
    LT[(size_t)(1 * CT + t) * N_TOT + r] = l;
    if (c1 < CT) {
        float v = (c1 < C) ? v1 : ((c1 == C) ? 1.0f : 0.0f);
        split_bf16(v, h, l);
        LT[(size_t)(0 * CT + c1) * N_TOT + r] = h;
        LT[(size_t)(1 * CT + c1) * N_TOT + r] = l;
    }
    float bv = v0; int bi = t;
    if (c1 < C && v1 > bv) { bv = v1; bi = c1; }
    #pragma unroll
    for (int m = 32; m; m >>= 1) {
        float ov = __shfl_xor(bv, m);
        int   oi = __shfl_xor(bi, m);
        if (ov > bv || (ov == bv && oi < bi)) { bv = ov; bi = oi; }
    }
    if (t == 0) predB[r] = bi;
}

// ---------------------------------------------------------------------------
__global__ void copy_oh(const float4* __restrict__ oh, float4* __restrict__ out)
{
    for (int i = blockIdx.x * blockDim.x + threadIdx.x; i < N_LB * C / 4;
         i += gridDim.x * blockDim.x)
        out[i] = oh[i];
}

// ---------------------------------------------------------------------------
// attn_mfma: flash-fused sim->softmax->PV, both GEMMs on matrix cores via
// split-bf16 3-term products (hi*hi + hi*lo + lo*hi; ~2^-17 rel err).
// Fixed softmax shift 1/tau = 10 (diagonal dominance of normalized feats).
// 256 blocks x 512 thr (8 waves): wave (m, nh) = M-tile m (16 q-rows),
// key-half nh (32 of 64 chunk keys). mfma_f32_16x16x32_bf16 fragments:
//   A: row = lane&15, k = (lane>>4)*8 + i;  B: col = lane&15, same k
//   C/D: col = lane&15, row = (lane>>4)*4 + reg      [learn_hip m89]
// All LDS tiles XOR-swizzled (byte ^= (row&7)<<4) -> frag reads ~conflict-free.
// ---------------------------------------------------------------------------
#define SK_BYTES  (64 * 512)    // key tile: 64 rows x [hi 256B | lo 256B]
#define SLT_BYTES (112 * 256)   // L^T tile: 112 cls x [hi 128B | lo 128B]
#define SP_BYTES  (2 * 64 * 128) // P planes: [pl][q 64][key 64 x 2B]

__launch_bounds__(512)
__global__ void attn_mfma(const u16* __restrict__ F2, const u16* __restrict__ LT,
                          float* __restrict__ out)
{
    __shared__ __align__(16) char sK[SK_BYTES];
    __shared__ __align__(16) char sLT[SLT_BYTES];
    __shared__ __align__(16) char sP[SP_BYTES];
    __shared__ float sInv[64];

    const int tid  = threadIdx.x;
    const int lane = tid & 63;
    const int w    = tid >> 6;      // 0..7
    const int m    = w >> 1;        // M-tile
    const int nh   = w & 1;         // key half
    const int g    = lane >> 4;     // k-group
    const int lr   = lane & 15;
    const int r0   = blockIdx.x * 64;

    // zero-fill sLT class rows 104..111 once (never restaged)
    if (tid < 128) {
        int row = 104 + (tid >> 4), gr = tid & 15;
        *(f32x4*)(sLT + row * 256 + gr * 16) = f32x4{0, 0, 0, 0};
    }

    // Q fragments (registers, hi/lo): q-row = r0 + m*16 + lr
    short8 qhi[4], qlo[4];
    {
        const char* base = (const char*)F2 + (size_t)(r0 + m * 16 + lr) * 512;
        #pragma unroll
        for (int ks = 0; ks < 4; ++ks) {
            qhi[ks] = *(const short8*)(base + ks * 64 + g * 16);
            qlo[ks] = *(const short8*)(base + 256 + ks * 64 + g * 16);
        }
    }

    f32x4 o[7];
    #pragma unroll
    for (int nt = 0; nt < 7; ++nt) o[nt] = f32x4{0, 0, 0, 0};

    for (int ch = 0; ch < 256; ++ch) {
        const int c0 = ch * 64;
        __syncthreads();                       // prev chunk done with sK/sLT/sP
        #pragma unroll
        for (int it = 0; it < 4; ++it) {       // stage key tile (32 KB)
            int idx = tid + it * 512;
            int row = idx >> 5, b = (idx & 31) << 4;
            short8 v = *(const short8*)((const char*)F2 + (size_t)(c0 + row) * 512 + b);
            *(short8*)(sK + row * 512 + (b ^ ((row & 7) << 4))) = v;
        }
        #pragma unroll
        for (int it = 0; it < 4; ++it) {       // stage L^T tile (26 KB)
            int idx = tid + it * 512;
            if (idx < 1664) {
                int row = idx >> 4, b = (idx & 15) << 4;
                int pl = b >> 7, kb = b & 127;
                const char* src = (const char*)LT +
                    ((size_t)(pl * CT + row) * N_TOT + c0) * 2 + kb;
                short8 v = *(const short8*)src;
                *(short8*)(sLT + row * 256 + (b ^ ((row & 7) << 4))) = v;
            }
        }
        __syncthreads();

        // ---- S = Q.K^T over this wave's key half (2 N-tiles) ----
        #pragma unroll
        for (int nt = 0; nt < 2; ++nt) {
            const int krow = nh * 32 + nt * 16 + lr;
            const int sw = (krow & 7) << 4;
            short8 bhi[4], blo[4];
            #pragma unroll
            for (int ks = 0; ks < 4; ++ks) {
                int bo = ks * 64 + g * 16;
                bhi[ks] = *(const short8*)(sK + krow * 512 + (bo ^ sw));
                blo[ks] = *(const short8*)(sK + krow * 512 + ((256 + bo) ^ sw));
            }
            f32x4 acc = {0, 0, 0, 0};
            #pragma unroll
            for (int ks = 0; ks < 4; ++ks)
                acc = __builtin_amdgcn_mfma_f32_16x16x32_bf16(qhi[ks], bhi[ks], acc, 0, 0, 0);
            #pragma unroll
            for (int ks = 0; ks < 4; ++ks)
                acc = __builtin_amdgcn_mfma_f32_16x16x32_bf16(qhi[ks], blo[ks], acc, 0, 0, 0);
            #pragma unroll
            for (int ks = 0; ks < 4; ++ks)
                acc = __builtin_amdgcn_mfma_f32_16x16x32_bf16(qlo[ks], bhi[ks], acc, 0, 0, 0);
            // exp(10 s - 10), split, store P planes
            #pragma unroll
            for (int reg = 0; reg < 4; ++reg) {
                int q = m * 16 + g * 4 + reg;
                int key = nh * 32 + nt * 16 + lr;
                float p = __expf(10.0f * acc[reg] - 10.0f);
                u16 h, l;
                split_bf16(p, h, l);
                int swq = (q & 7) << 4;
                *(u16*)(sP + q * 128 + ((key * 2) ^ swq)) = h;
                *(u16*)(sP + 8192 + q * 128 + ((key * 2) ^ swq)) = l;
            }
        }
        __syncthreads();                       // P fully written

        // ---- PV: out += P . Ltile over this wave's key half ----
        const int qA = m * 16 + lr;
        const int swA = (qA & 7) << 4;
        const int ko = nh * 64 + g * 16;       // byte offset of 8-key granule
        short8 phi = *(const short8*)(sP + qA * 128 + (ko ^ swA));
        short8 plo = *(const short8*)(sP + 8192 + qA * 128 + (ko ^ swA));
        #pragma unroll
        for (int nt = 0; nt < 7; ++nt) {
            int cls = nt * 16 + lr;
            int swc = (cls & 7) << 4;
            int bo = nh * 64 + g * 16;
            short8 lhi = *(const short8*)(sLT + cls * 256 + (bo ^ swc));
            short8 llo = *(const short8*)(sLT + cls * 256 + ((128 + bo) ^ swc));
            o[nt] = __builtin_amdgcn_mfma_f32_16x16x32_bf16(phi, lhi, o[nt], 0, 0, 0);
            o[nt] = __builtin_amdgcn_mfma_f32_16x16x32_bf16(phi, llo, o[nt], 0, 0, 0);
            o[nt] = __builtin_amdgcn_mfma_f32_16x16x32_bf16(plo, lhi, o[nt], 0, 0, 0);
        }
    }

    // ---- epilogue: reduce key-half partials, normalize, store ----
    __syncthreads();
    float* red = (float*)sK;                   // 28 KB scratch, sK dead now
    if (nh == 1) {
        #pragma unroll
        for (int nt = 0; nt < 7; ++nt)
            #pragma unroll
            for (int reg = 0; reg < 4; ++reg)
                red[((m * 7 + nt) * 4 + reg) * 64 + lane] = o[nt][reg];
    }
    __syncthreads();
    if (nh == 0) {
        #pragma unroll
        for (int nt = 0; nt < 7; ++nt)
            #pragma unroll
            for (int reg = 0; reg < 4; ++reg)
                o[nt][reg] += red[((m * 7 + nt) * 4 + reg) * 64 + lane];
        if (lr == 4) {                         // class 100 = denominator (nt 6, col 4)
            #pragma unroll
            for (int reg = 0; reg < 4; ++reg)
                sInv[m * 16 + g * 4 + reg] = 1.0f / o[6][reg];
        }
    }
    __syncthreads();
    if (nh == 0) {
        #pragma unroll
        for (int nt = 0; nt < 7; ++nt) {
            int cls = nt * 16 + lr;
            if (cls < C) {
                #pragma unroll
                for (int reg = 0; reg < 4; ++reg) {
                    int row = r0 + m * 16 + g * 4 + reg;
                    out[OFF_OUTLB + (size_t)row * C + cls] =
                        o[nt][reg] * sInv[m * 16 + g * 4 + reg];
                }
            }
        }
    }
}

// ---------------------------------------------------------------------------
__global__ void argmax_after(const float* __restrict__ LA, int* __restrict__ predA)
{
    const int lane = threadIdx.x & 63;
    const int row  = blockIdx.x * 4 + (threadIdx.x >> 6);
    float bv = LA[row * C + lane]; int bi = lane;
    const int c1 = lane + 64;
    if (c1 < C) { float v1 = LA[row * C + c1]; if (v1 > bv) { bv = v1; bi = c1; } }
    #pragma unroll
    for (int m = 32; m; m >>= 1) {
        float ov = __shfl_xor(bv, m);
        int   oi = __shfl_xor(bi, m);
        if (ov > bv || (ov == bv && oi < bi)) { bv = ov; bi = oi; }
    }
    if (lane == 0) predA[row] = bi;
}

// ---------------------------------------------------------------------------
__global__ void finalize(const int* __restrict__ predA, const int* __restrict__ predB,
                         float* __restrict__ out)
{
    __shared__ int sm[256];
    const int t = threadIdx.x;
    int local = N_TOT;
    for (int r = t; r < N_TOT; r += 256)
        if (predA[r] != predB[r] && r < local) local = r;
    sm[t] = local;
    __syncthreads();
    for (int s = 128; s; s >>= 1) {
        if (t < s) sm[t] = min(sm[t], sm[t + s]);
        __syncthreads();
    }
    if (t == 0) {
        int first = (sm[0] == N_TOT) ? 0 : sm[0];
        out[OFF_SCAL + 0] = (float)first;
        out[OFF_SCAL + 1] = (float)first;
        out[OFF_SCAL + 2] = (float)predB[first];
        out[OFF_SCAL + 3] = (float)predA[first];
        out[OFF_SCAL + 4] = (float)predB[first];
        out[OFF_SCAL + 5] = (float)predA[first];
    }
}

// ---------------------------------------------------------------------------
extern "C" void kernel_launch(void* const* d_in, const int* in_sizes, int n_in,
                              void* d_out, int out_size, void* d_ws, size_t ws_size,
                              hipStream_t stream)
{
    const float* anchor   = (const float*)d_in[0];
    const float* positive = (const float*)d_in[1];
    const float* lbf      = (const float*)d_in[2];
    const float* oh       = (const float*)d_in[3];
    const float* l_lb     = (const float*)d_in[4];
    const float* l_u1     = (const float*)d_in[5];
    const float* l_u2     = (const float*)d_in[6];
    float* out = (float*)d_out;

    u16* F2 = (u16*)d_ws;                            // 8 MB
    u16* LT = F2 + (size_t)N_TOT * 256;              // 2*104*16384*2 = 6.8 MB
    int* predB = (int*)(LT + (size_t)2 * CT * N_TOT);
    int* predA = predB + N_TOT;

    prep_feats <<<N_TOT, 64, 0, stream>>>(anchor, positive, lbf, F2, out);
    prep_logits<<<N_TOT, 64, 0, stream>>>(l_lb, l_u1, l_u2, LT, predB);
    copy_oh    <<<200, 256, 0, stream>>>((const float4*)oh, (float4*)&out[OFF_OH]);
    attn_mfma  <<<256, 512, 0, stream>>>(F2, LT, out);
    argmax_after<<<N_TOT / 4, 256, 0, stream>>>(&out[OFF_OUTLB], predA);
    finalize   <<<1, 256, 0, stream>>>(predA, predB, out);
}

// Round 5
// 554.019 us; speedup vs baseline: 5.2024x; 1.6550x over previous
//
#include <hip/hip_runtime.h>
#include <hip/hip_bf16.h>

typedef unsigned short u16;
typedef unsigned int u32;
typedef __attribute__((ext_vector_type(8))) short short8;
typedef __attribute__((ext_vector_type(4))) float f32x4;

#define N_LB   4096
#define N_ULB  6144
#define N_TOT  16384
#define D      128
#define C      100
#define CT     104   // classes stored in LT (100 logits + denom@100 + 3 zero)

// d_out element offsets (f32 elements, reference return order)
#define OFF_ANCHOR 0
#define OFF_POS    786432
#define OFF_LBF    1572864
#define OFF_OH     2097152
#define OFF_OUTLB  2506752   // out_lb / out_ulb_1 / out_ulb_2 row-contiguous
#define OFF_SCAL   4145152

__device__ __forceinline__ void split_bf16(float x, u16& hi, u16& lo) {
    __hip_bfloat16 h = __float2bfloat16(x);
    float r = x - __bfloat162float(h);
    __hip_bfloat16 l = __float2bfloat16(r);
    hi = __bfloat16_as_ushort(h);
    lo = __bfloat16_as_ushort(l);
}

// async global->LDS DMA, 16B per lane (wave-uniform LDS base + lane*16)
__device__ __forceinline__ void gl_lds16(const char* g, char* l) {
    __builtin_amdgcn_global_load_lds(
        (const __attribute__((address_space(1))) u32*)g,
        (__attribute__((address_space(3))) u32*)l, 16, 0, 0);
}

// ---------------------------------------------------------------------------
// prep_feats: L2-normalize rows; split to bf16 hi/lo planes in ws
// F2[16384][256] u16 (row = [hi 0..127 | lo 128..255]); exact f32 passthrough.
// ---------------------------------------------------------------------------
__global__ void prep_feats(const float* __restrict__ anchor,
                           const float* __restrict__ positive,
                           const float* __restrict__ lbf,
                           u16* __restrict__ F2,
                           float* __restrict__ out)
{
    const int r = blockIdx.x;
    const int t = threadIdx.x;   // 0..63
    const float* src; int rr, ptbase;
    if (r < N_LB)              { src = lbf;      rr = r;                ptbase = OFF_LBF; }
    else if (r < N_LB + N_ULB) { src = anchor;   rr = r - N_LB;         ptbase = OFF_ANCHOR; }
    else                       { src = positive; rr = r - N_LB - N_ULB; ptbase = OFF_POS; }
    float2 x = *(const float2*)&src[rr * D + 2 * t];
    float ss = x.x * x.x + x.y * x.y;
    #pragma unroll
    for (int m = 32; m; m >>= 1) ss += __shfl_xor(ss, m);
    float inv = 1.0f / fmaxf(sqrtf(ss), 1e-12f);
    float y0 = x.x * inv, y1 = x.y * inv;
    u16 h0, l0, h1, l1;
    split_bf16(y0, h0, l0);
    split_bf16(y1, h1, l1);
    *(u32*)&F2[r * 256 + 2 * t]       = (u32)h0 | ((u32)h1 << 16);
    *(u32*)&F2[r * 256 + 128 + 2 * t] = (u32)l0 | ((u32)l1 << 16);
    *(float2*)&out[ptbase + rr * D + 2 * t] = x;   // exact bit copy
}

// ---------------------------------------------------------------------------
// prep_logits: transposed split-bf16 LT[pl][cls][key]; cls 100 = 1.0 (folded
// softmax denominator). pred_before via exact first-occurrence argmax.
// ---------------------------------------------------------------------------
__global__ void prep_logits(const float* __restrict__ l_lb,
                            const float* __restrict__ l_u1,
                            const float* __restrict__ l_u2,
                            u16* __restrict__ LT,
                            int* __restrict__ predB)
{
    const int r = blockIdx.x;
    const int t = threadIdx.x;   // 0..63
    const float* src; int rr;
    if (r < N_LB)              { src = l_lb; rr = r; }
    else if (r < N_LB + N_ULB) { src = l_u1; rr = r - N_LB; }
    else                       { src = l_u2; rr = r - N_LB - N_ULB; }
    float v0 = src[rr * C + t];
    const int c1 = t + 64;
    float v1 = (c1 < C) ? src[rr * C + c1] : 0.0f;
    u16 h, l;
    split_bf16(v0, h, l);
    LT[(size_t)(0 * CT + t) * N_TOT + r] = h;
    LT[(size_t)(1 * CT + t) * N_TOT + r] = l;
    if (c1 < CT) {
        float v = (c1 < C) ? v1 : ((c1 == C) ? 1.0f : 0.0f);
        split_bf16(v, h, l);
        LT[(size_t)(0 * CT + c1) * N_TOT + r] = h;
        LT[(size_t)(1 * CT + c1) * N_TOT + r] = l;
    }
    float bv = v0; int bi = t;
    if (c1 < C && v1 > bv) { bv = v1; bi = c1; }
    #pragma unroll
    for (int m = 32; m; m >>= 1) {
        float ov = __shfl_xor(bv, m);
        int   oi = __shfl_xor(bi, m);
        if (ov > bv || (ov == bv && oi < bi)) { bv = ov; bi = oi; }
    }
    if (t == 0) predB[r] = bi;
}

// ---------------------------------------------------------------------------
__global__ void copy_oh(const float4* __restrict__ oh, float4* __restrict__ out)
{
    for (int i = blockIdx.x * blockDim.x + threadIdx.x; i < N_LB * C / 4;
         i += gridDim.x * blockDim.x)
        out[i] = oh[i];
}

// ---------------------------------------------------------------------------
// attn_mfma: flash-fused sim->softmax->PV on matrix cores (split-bf16 3-term).
// Round-5 change: 2-phase software pipeline — double-buffered sK/sLT staged
// via async global_load_lds (pre-swizzled SOURCE, linear LDS dest, swizzled
// reads: both-sides rule) issued right after B1, draining at B2's implicit
// vmcnt(0), so DMA latency hides under the S-phase.
// Per chunk: B1 | issue DMA(t+1) | S:QK^T+exp->sP | B2 | PV.
// ---------------------------------------------------------------------------
#define SK_BYTES  (64 * 512)     // key tile: 64 rows x [hi 256B | lo 256B]
#define SLT_BYTES (112 * 256)    // L^T tile: 112 cls x [hi 128B | lo 128B]
#define SP_BYTES  (2 * 64 * 128) // P planes: [pl][q 64][key 64 x 2B]

__launch_bounds__(512)
__global__ void attn_mfma(const u16* __restrict__ F2, const u16* __restrict__ LT,
                          float* __restrict__ out)
{
    __shared__ __align__(16) char sK[2][SK_BYTES];    // 64 KB
    __shared__ __align__(16) char sLT[2][SLT_BYTES];  // 56 KB
    __shared__ __align__(16) char sP[SP_BYTES];       // 16 KB
    __shared__ float sInv[64];

    const int tid  = threadIdx.x;
    const int lane = tid & 63;
    const int w    = tid >> 6;      // 0..7
    const int m    = w >> 1;        // M-tile
    const int nh   = w & 1;         // key half
    const int g    = lane >> 4;     // k-group
    const int lr   = lane & 15;
    const int r0   = blockIdx.x * 64;

    const char* F2b = (const char*)F2;
    const char* LTb = (const char*)LT;

    // zero-fill sLT class rows 104..111 (both buffers) once; never restaged
    if (tid < 256) {
        int bf = tid >> 7, row = 104 + ((tid & 127) >> 4), gr = tid & 15;
        *(f32x4*)(sLT[bf] + row * 256 + gr * 16) = f32x4{0, 0, 0, 0};
    }

    // Q fragments (registers, hi/lo): q-row = r0 + m*16 + lr
    short8 qhi[4], qlo[4];
    {
        const char* base = F2b + (size_t)(r0 + m * 16 + lr) * 512;
        #pragma unroll
        for (int ks = 0; ks < 4; ++ks) {
            qhi[ks] = *(const short8*)(base + ks * 64 + g * 16);
            qlo[ks] = *(const short8*)(base + 256 + ks * 64 + g * 16);
        }
    }

    // ---- prologue: stage chunk 0 into buffer 0 ----
    #pragma unroll
    for (int it = 0; it < 4; ++it) {
        int idx = tid + it * 512;
        int row = idx >> 5, b = (idx & 31) << 4;
        gl_lds16(F2b + (size_t)row * 512 + (b ^ ((row & 7) << 4)), sK[0] + idx * 16);
    }
    #pragma unroll
    for (int it = 0; it < 4; ++it) {
        int idx = tid + it * 512;
        if (idx < 1664) {
            int row = idx >> 4, b = (idx & 15) << 4;
            int b2 = b ^ ((row & 7) << 4);
            int pl = b2 >> 7, kb = b2 & 127;
            gl_lds16(LTb + ((size_t)(pl * CT + row) * N_TOT) * 2 + kb, sLT[0] + idx * 16);
        }
    }

    f32x4 o[7];
    #pragma unroll
    for (int nt = 0; nt < 7; ++nt) o[nt] = f32x4{0, 0, 0, 0};

    for (int ch = 0; ch < 256; ++ch) {
        const int cur = ch & 1;
        __syncthreads();                       // B1: tile(ch) in LDS; PV(ch-1) done

        // ---- issue async staging for chunk ch+1 into the other buffer ----
        if (ch + 1 < 256) {
            const int cn = (ch + 1) * 64;
            char* dK = sK[cur ^ 1];
            char* dL = sLT[cur ^ 1];
            #pragma unroll
            for (int it = 0; it < 4; ++it) {
                int idx = tid + it * 512;
                int row = idx >> 5, b = (idx & 31) << 4;
                gl_lds16(F2b + (size_t)(cn + row) * 512 + (b ^ ((row & 7) << 4)),
                         dK + idx * 16);
            }
            #pragma unroll
            for (int it = 0; it < 4; ++it) {
                int idx = tid + it * 512;
                if (idx < 1664) {
                    int row = idx >> 4, b = (idx & 15) << 4;
                    int b2 = b ^ ((row & 7) << 4);
                    int pl = b2 >> 7, kb = b2 & 127;
                    gl_lds16(LTb + ((size_t)(pl * CT + row) * N_TOT + cn) * 2 + kb,
                             dL + idx * 16);
                }
            }
        }

        // ---- S = Q.K^T over this wave's key half (2 N-tiles) ----
        const char* K = sK[cur];
        #pragma unroll
        for (int nt = 0; nt < 2; ++nt) {
            const int krow = nh * 32 + nt * 16 + lr;
            const int sw = (krow & 7) << 4;
            short8 bhi[4], blo[4];
            #pragma unroll
            for (int ks = 0; ks < 4; ++ks) {
                int bo = ks * 64 + g * 16;
                bhi[ks] = *(const short8*)(K + krow * 512 + (bo ^ sw));
                blo[ks] = *(const short8*)(K + krow * 512 + ((256 + bo) ^ sw));
            }
            f32x4 acc = {0, 0, 0, 0};
            #pragma unroll
            for (int ks = 0; ks < 4; ++ks)
                acc = __builtin_amdgcn_mfma_f32_16x16x32_bf16(qhi[ks], bhi[ks], acc, 0, 0, 0);
            #pragma unroll
            for (int ks = 0; ks < 4; ++ks)
                acc = __builtin_amdgcn_mfma_f32_16x16x32_bf16(qhi[ks], blo[ks], acc, 0, 0, 0);
            #pragma unroll
            for (int ks = 0; ks < 4; ++ks)
                acc = __builtin_amdgcn_mfma_f32_16x16x32_bf16(qlo[ks], bhi[ks], acc, 0, 0, 0);
            // exp(10 s - 10), split, store P planes
            #pragma unroll
            for (int reg = 0; reg < 4; ++reg) {
                int q = m * 16 + g * 4 + reg;
                int key = nh * 32 + nt * 16 + lr;
                float p = __expf(10.0f * acc[reg] - 10.0f);
                u16 h, l;
                split_bf16(p, h, l);
                int swq = (q & 7) << 4;
                *(u16*)(sP + q * 128 + ((key * 2) ^ swq)) = h;
                *(u16*)(sP + 8192 + q * 128 + ((key * 2) ^ swq)) = l;
            }
        }
        __syncthreads();                       // B2: sP ready (drains DMA too)

        // ---- PV: out += P . Ltile over this wave's key half ----
        const char* Lt = sLT[cur];
        const int qA = m * 16 + lr;
        const int swA = (qA & 7) << 4;
        const int ko = nh * 64 + g * 16;       // byte offset of 8-key granule
        short8 phi = *(const short8*)(sP + qA * 128 + (ko ^ swA));
        short8 plo = *(const short8*)(sP + 8192 + qA * 128 + (ko ^ swA));
        #pragma unroll
        for (int nt = 0; nt < 7; ++nt) {
            int cls = nt * 16 + lr;
            int swc = (cls & 7) << 4;
            int bo = nh * 64 + g * 16;
            short8 lhi = *(const short8*)(Lt + cls * 256 + (bo ^ swc));
            short8 llo = *(const short8*)(Lt + cls * 256 + ((128 + bo) ^ swc));
            o[nt] = __builtin_amdgcn_mfma_f32_16x16x32_bf16(phi, lhi, o[nt], 0, 0, 0);
            o[nt] = __builtin_amdgcn_mfma_f32_16x16x32_bf16(phi, llo, o[nt], 0, 0, 0);
            o[nt] = __builtin_amdgcn_mfma_f32_16x16x32_bf16(plo, lhi, o[nt], 0, 0, 0);
        }
    }

    // ---- epilogue: reduce key-half partials, normalize, store ----
    __syncthreads();
    float* red = (float*)&sK[0][0];            // 28 KB scratch, sK dead now
    if (nh == 1) {
        #pragma unroll
        for (int nt = 0; nt < 7; ++nt)
            #pragma unroll
            for (int reg = 0; reg < 4; ++reg)
                red[((m * 7 + nt) * 4 + reg) * 64 + lane] = o[nt][reg];
    }
    __syncthreads();
    if (nh == 0) {
        #pragma unroll
        for (int nt = 0; nt < 7; ++nt)
            #pragma unroll
            for (int reg = 0; reg < 4; ++reg)
                o[nt][reg] += red[((m * 7 + nt) * 4 + reg) * 64 + lane];
        if (lr == 4) {                         // class 100 = denominator (nt 6, col 4)
            #pragma unroll
            for (int reg = 0; reg < 4; ++reg)
                sInv[m * 16 + g * 4 + reg] = 1.0f / o[6][reg];
        }
    }
    __syncthreads();
    if (nh == 0) {
        #pragma unroll
        for (int nt = 0; nt < 7; ++nt) {
            int cls = nt * 16 + lr;
            if (cls < C) {
                #pragma unroll
                for (int reg = 0; reg < 4; ++reg) {
                    int row = r0 + m * 16 + g * 4 + reg;
                    out[OFF_OUTLB + (size_t)row * C + cls] =
                        o[nt][reg] * sInv[m * 16 + g * 4 + reg];
                }
            }
        }
    }
}

// ---------------------------------------------------------------------------
__global__ void argmax_after(const float* __restrict__ LA, int* __restrict__ predA)
{
    const int lane = threadIdx.x & 63;
    const int row  = blockIdx.x * 4 + (threadIdx.x >> 6);
    float bv = LA[row * C + lane]; int bi = lane;
    const int c1 = lane + 64;
    if (c1 < C) { float v1 = LA[row * C + c1]; if (v1 > bv) { bv = v1; bi = c1; } }
    #pragma unroll
    for (int m = 32; m; m >>= 1) {
        float ov = __shfl_xor(bv, m);
        int   oi = __shfl_xor(bi, m);
        if (ov > bv || (ov == bv && oi < bi)) { bv = ov; bi = oi; }
    }
    if (lane == 0) predA[row] = bi;
}

// ---------------------------------------------------------------------------
__global__ void finalize(const int* __restrict__ predA, const int* __restrict__ predB,
                         float* __restrict__ out)
{
    __shared__ int sm[256];
    const int t = threadIdx.x;
    int local = N_TOT;
    for (int r = t; r < N_TOT; r += 256)
        if (predA[r] != predB[r] && r < local) local = r;
    sm[t] = local;
    __syncthreads();
    for (int s = 128; s; s >>= 1) {
        if (t < s) sm[t] = min(sm[t], sm[t + s]);
        __syncthreads();
    }
    if (t == 0) {
        int first = (sm[0] == N_TOT) ? 0 : sm[0];
        out[OFF_SCAL + 0] = (float)first;
        out[OFF_SCAL + 1] = (float)first;
        out[OFF_SCAL + 2] = (float)predB[first];
        out[OFF_SCAL + 3] = (float)predA[first];
        out[OFF_SCAL + 4] = (float)predB[first];
        out[OFF_SCAL + 5] = (float)predA[first];
    }
}

// ---------------------------------------------------------------------------
extern "C" void kernel_launch(void* const* d_in, const int* in_sizes, int n_in,
                              void* d_out, int out_size, void* d_ws, size_t ws_size,
                              hipStream_t stream)
{
    const float* anchor   = (const float*)d_in[0];
    const float* positive = (const float*)d_in[1];
    const float* lbf      = (const float*)d_in[2];
    const float* oh       = (const float*)d_in[3];
    const float* l_lb     = (const float*)d_in[4];
    const float* l_u1     = (const float*)d_in[5];
    const float* l_u2     = (const float*)d_in[6];
    float* out = (float*)d_out;

    u16* F2 = (u16*)d_ws;                            // 8 MB
    u16* LT = F2 + (size_t)N_TOT * 256;              // 6.8 MB
    int* predB = (int*)(LT + (size_t)2 * CT * N_TOT);
    int* predA = predB + N_TOT;

    prep_feats <<<N_TOT, 64, 0, stream>>>(anchor, positive, lbf, F2, out);
    prep_logits<<<N_TOT, 64, 0, stream>>>(l_lb, l_u1, l_u2, LT, predB);
    copy_oh    <<<200, 256, 0, stream>>>((const float4*)oh, (float4*)&out[OFF_OH]);
    attn_mfma  <<<256, 512, 0, stream>>>(F2, LT, out);
    argmax_after<<<N_TOT / 4, 256, 0, stream>>>(&out[OFF_OUTLB], predA);
    finalize   <<<1, 256, 0, stream>>>(predA, predB, out);
}

// Round 6
// 541.217 us; speedup vs baseline: 5.3254x; 1.0237x over previous
//
#include <hip/hip_runtime.h>
#include <hip/hip_bf16.h>

typedef unsigned short u16;
typedef unsigned int u32;
typedef __attribute__((ext_vector_type(8))) short short8;
typedef __attribute__((ext_vector_type(4))) float f32x4;

#define N_LB   4096
#define N_ULB  6144
#define N_TOT  16384
#define D      128
#define C      100
#define CT     104   // classes stored in LT (100 logits + denom@100 + 3 zero)

// d_out element offsets (f32 elements, reference return order)
#define OFF_ANCHOR 0
#define OFF_POS    786432
#define OFF_LBF    1572864
#define OFF_OH     2097152
#define OFF_OUTLB  2506752   // out_lb / out_ulb_1 / out_ulb_2 row-contiguous
#define OFF_SCAL   4145152

__device__ __forceinline__ void split_bf16(float x, u16& hi, u16& lo) {
    __hip_bfloat16 h = __float2bfloat16(x);
    float r = x - __bfloat162float(h);
    __hip_bfloat16 l = __float2bfloat16(r);
    hi = __bfloat16_as_ushort(h);
    lo = __bfloat16_as_ushort(l);
}

// async global->LDS DMA, 16B per lane (wave-uniform LDS base + lane*16)
__device__ __forceinline__ void gl_lds16(const char* g, char* l) {
    __builtin_amdgcn_global_load_lds(
        (const __attribute__((address_space(1))) u32*)g,
        (__attribute__((address_space(3))) u32*)l, 16, 0, 0);
}

// ---------------------------------------------------------------------------
// prep_feats: L2-normalize rows; split to bf16 hi/lo planes in ws
// F2[16384][256] u16 (row = [hi 0..127 | lo 128..255]); exact f32 passthrough.
// ---------------------------------------------------------------------------
__global__ void prep_feats(const float* __restrict__ anchor,
                           const float* __restrict__ positive,
                           const float* __restrict__ lbf,
                           u16* __restrict__ F2,
                           float* __restrict__ out)
{
    const int r = blockIdx.x;
    const int t = threadIdx.x;   // 0..63
    const float* src; int rr, ptbase;
    if (r < N_LB)              { src = lbf;      rr = r;                ptbase = OFF_LBF; }
    else if (r < N_LB + N_ULB) { src = anchor;   rr = r - N_LB;         ptbase = OFF_ANCHOR; }
    else                       { src = positive; rr = r - N_LB - N_ULB; ptbase = OFF_POS; }
    float2 x = *(const float2*)&src[rr * D + 2 * t];
    float ss = x.x * x.x + x.y * x.y;
    #pragma unroll
    for (int m = 32; m; m >>= 1) ss += __shfl_xor(ss, m);
    float inv = 1.0f / fmaxf(sqrtf(ss), 1e-12f);
    float y0 = x.x * inv, y1 = x.y * inv;
    u16 h0, l0, h1, l1;
    split_bf16(y0, h0, l0);
    split_bf16(y1, h1, l1);
    *(u32*)&F2[r * 256 + 2 * t]       = (u32)h0 | ((u32)h1 << 16);
    *(u32*)&F2[r * 256 + 128 + 2 * t] = (u32)l0 | ((u32)l1 << 16);
    *(float2*)&out[ptbase + rr * D + 2 * t] = x;   // exact bit copy
}

// ---------------------------------------------------------------------------
// prep_logits: transposed split-bf16 LT[pl][cls][key]; cls 100 = 1.0 (folded
// softmax denominator). pred_before via exact first-occurrence argmax.
// ---------------------------------------------------------------------------
__global__ void prep_logits(const float* __restrict__ l_lb,
                            const float* __restrict__ l_u1,
                            const float* __restrict__ l_u2,
                            u16* __restrict__ LT,
                            int* __restrict__ predB)
{
    const int r = blockIdx.x;
    const int t = threadIdx.x;   // 0..63
    const float* src; int rr;
    if (r < N_LB)              { src = l_lb; rr = r; }
    else if (r < N_LB + N_ULB) { src = l_u1; rr = r - N_LB; }
    else                       { src = l_u2; rr = r - N_LB - N_ULB; }
    float v0 = src[rr * C + t];
    const int c1 = t + 64;
    float v1 = (c1 < C) ? src[rr * C + c1] : 0.0f;
    u16 h, l;
    split_bf16(v0, h, l);
    LT[(size_t)(0 * CT + t) * N_TOT + r] = h;
    LT[(size_t)(1 * CT + t) * N_TOT + r] = l;
    if (c1 < CT) {
        float v = (c1 < C) ? v1 : ((c1 == C) ? 1.0f : 0.0f);
        split_bf16(v, h, l);
        LT[(size_t)(0 * CT + c1) * N_TOT + r] = h;
        LT[(size_t)(1 * CT + c1) * N_TOT + r] = l;
    }
    float bv = v0; int bi = t;
    if (c1 < C && v1 > bv) { bv = v1; bi = c1; }
    #pragma unroll
    for (int m = 32; m; m >>= 1) {
        float ov = __shfl_xor(bv, m);
        int   oi = __shfl_xor(bi, m);
        if (ov > bv || (ov == bv && oi < bi)) { bv = ov; bi = oi; }
    }
    if (t == 0) predB[r] = bi;
}

// ---------------------------------------------------------------------------
__global__ void copy_oh(const float4* __restrict__ oh, float4* __restrict__ out)
{
    for (int i = blockIdx.x * blockDim.x + threadIdx.x; i < N_LB * C / 4;
         i += gridDim.x * blockDim.x)
        out[i] = oh[i];
}

// ---------------------------------------------------------------------------
// attn_mfma: flash-fused sim->softmax->PV on matrix cores (split-bf16 3-term,
// fixed softmax shift 1/tau = 10), 2-phase DMA pipeline (unchanged from r5).
// Round-6 change: 32 q-rows per wave to halve fragment-read redundancy.
//   S : waves (mh2 x nq4): 32q x 16k, B-reads 8 b128 (was 16), 24 MFMA.
//   PV: waves (mh2 x nh2 x clsh2): 32q x {64,48}cls x 32keys, 12/10 b128.
// Fragment layouts / swizzles / sP format identical to round 5.
// ---------------------------------------------------------------------------
#define SK_BYTES  (64 * 512)     // key tile: 64 rows x [hi 256B | lo 256B]
#define SLT_BYTES (112 * 256)    // L^T tile: 112 cls x [hi 128B | lo 128B]
#define SP_BYTES  (2 * 64 * 128) // P planes: [pl][q 64][key 64 x 2B]

__launch_bounds__(512)
__global__ void attn_mfma(const u16* __restrict__ F2, const u16* __restrict__ LT,
                          float* __restrict__ out)
{
    __shared__ __align__(16) char sK[2][SK_BYTES];    // 64 KB
    __shared__ __align__(16) char sLT[2][SLT_BYTES];  // 56 KB
    __shared__ __align__(16) char sP[SP_BYTES];       // 16 KB
    __shared__ float sInv[64];

    const int tid  = threadIdx.x;
    const int lane = tid & 63;
    const int w    = tid >> 6;      // 0..7
    const int mh   = w >> 2;        // 32-row half owned by this wave
    const int nq   = w & 3;         // S: 16-key column
    const int nh   = (w >> 1) & 1;  // PV: 32-key half
    const int clsh = w & 1;         // PV: class half (tiles 0-3 / 4-6)
    const int g    = lane >> 4;     // k-group
    const int lr   = lane & 15;
    const int r0   = blockIdx.x * 64;

    const char* F2b = (const char*)F2;
    const char* LTb = (const char*)LT;

    // zero-fill sLT class rows 104..111 (both buffers) once; never restaged
    if (tid < 256) {
        int bf = tid >> 7, row = 104 + ((tid & 127) >> 4), gr = tid & 15;
        *(f32x4*)(sLT[bf] + row * 256 + gr * 16) = f32x4{0, 0, 0, 0};
    }

    // Q fragments (registers, hi/lo) for BOTH 16-row subtiles of this half
    short8 qhi[2][4], qlo[2][4];
    #pragma unroll
    for (int ms = 0; ms < 2; ++ms) {
        const char* base = F2b + (size_t)(r0 + mh * 32 + ms * 16 + lr) * 512;
        #pragma unroll
        for (int ks = 0; ks < 4; ++ks) {
            qhi[ms][ks] = *(const short8*)(base + ks * 64 + g * 16);
            qlo[ms][ks] = *(const short8*)(base + 256 + ks * 64 + g * 16);
        }
    }

    // ---- prologue: stage chunk 0 into buffer 0 ----
    #pragma unroll
    for (int it = 0; it < 4; ++it) {
        int idx = tid + it * 512;
        int row = idx >> 5, b = (idx & 31) << 4;
        gl_lds16(F2b + (size_t)row * 512 + (b ^ ((row & 7) << 4)), sK[0] + idx * 16);
    }
    #pragma unroll
    for (int it = 0; it < 4; ++it) {
        int idx = tid + it * 512;
        if (idx < 1664) {
            int row = idx >> 4, b = (idx & 15) << 4;
            int b2 = b ^ ((row & 7) << 4);
            int pl = b2 >> 7, kb = b2 & 127;
            gl_lds16(LTb + ((size_t)(pl * CT + row) * N_TOT) * 2 + kb, sLT[0] + idx * 16);
        }
    }

    f32x4 o[2][4];                  // [msub][cls-tile within half]
    #pragma unroll
    for (int ms = 0; ms < 2; ++ms)
        #pragma unroll
        for (int ct = 0; ct < 4; ++ct) o[ms][ct] = f32x4{0, 0, 0, 0};

    for (int ch = 0; ch < 256; ++ch) {
        const int cur = ch & 1;
        __syncthreads();                       // B1: tile(ch) in LDS; PV(ch-1) done

        // ---- issue async staging for chunk ch+1 into the other buffer ----
        if (ch + 1 < 256) {
            const int cn = (ch + 1) * 64;
            char* dK = sK[cur ^ 1];
            char* dL = sLT[cur ^ 1];
            #pragma unroll
            for (int it = 0; it < 4; ++it) {
                int idx = tid + it * 512;
                int row = idx >> 5, b = (idx & 31) << 4;
                gl_lds16(F2b + (size_t)(cn + row) * 512 + (b ^ ((row & 7) << 4)),
                         dK + idx * 16);
            }
            #pragma unroll
            for (int it = 0; it < 4; ++it) {
                int idx = tid + it * 512;
                if (idx < 1664) {
                    int row = idx >> 4, b = (idx & 15) << 4;
                    int b2 = b ^ ((row & 7) << 4);
                    int pl = b2 >> 7, kb = b2 & 127;
                    gl_lds16(LTb + ((size_t)(pl * CT + row) * N_TOT + cn) * 2 + kb,
                             dL + idx * 16);
                }
            }
        }

        // ---- S = Q.K^T : this wave's 32q x 16k tile pair ----
        {
            const char* K = sK[cur];
            const int krow = nq * 16 + lr;
            const int sw = (krow & 7) << 4;
            short8 bhi[4], blo[4];
            #pragma unroll
            for (int ks = 0; ks < 4; ++ks) {
                int bo = ks * 64 + g * 16;
                bhi[ks] = *(const short8*)(K + krow * 512 + (bo ^ sw));
                blo[ks] = *(const short8*)(K + krow * 512 + ((256 + bo) ^ sw));
            }
            #pragma unroll
            for (int ms = 0; ms < 2; ++ms) {
                f32x4 acc = {0, 0, 0, 0};
                #pragma unroll
                for (int ks = 0; ks < 4; ++ks)
                    acc = __builtin_amdgcn_mfma_f32_16x16x32_bf16(qhi[ms][ks], bhi[ks], acc, 0, 0, 0);
                #pragma unroll
                for (int ks = 0; ks < 4; ++ks)
                    acc = __builtin_amdgcn_mfma_f32_16x16x32_bf16(qhi[ms][ks], blo[ks], acc, 0, 0, 0);
                #pragma unroll
                for (int ks = 0; ks < 4; ++ks)
                    acc = __builtin_amdgcn_mfma_f32_16x16x32_bf16(qlo[ms][ks], bhi[ks], acc, 0, 0, 0);
                // exp(10 s - 10), split, store P planes
                #pragma unroll
                for (int reg = 0; reg < 4; ++reg) {
                    int q = mh * 32 + ms * 16 + g * 4 + reg;
                    int key = nq * 16 + lr;
                    float p = __expf(10.0f * acc[reg] - 10.0f);
                    u16 h, l;
                    split_bf16(p, h, l);
                    int swq = (q & 7) << 4;
                    *(u16*)(sP + q * 128 + ((key * 2) ^ swq)) = h;
                    *(u16*)(sP + 8192 + q * 128 + ((key * 2) ^ swq)) = l;
                }
            }
        }
        __syncthreads();                       // B2: sP ready (drains DMA too)

        // ---- PV: o[32q][cls-half] += P . Ltile over this wave's 32-key half ----
        {
            const char* Lt = sLT[cur];
            short8 phi[2], plo[2];
            #pragma unroll
            for (int ms = 0; ms < 2; ++ms) {
                int q = mh * 32 + ms * 16 + lr;
                int ko = (nh * 64 + g * 16) ^ ((q & 7) << 4);
                phi[ms] = *(const short8*)(sP + q * 128 + ko);
                plo[ms] = *(const short8*)(sP + 8192 + q * 128 + ko);
            }
            #pragma unroll
            for (int ct = 0; ct < 4; ++ct) {
                if (clsh == 0 || ct < 3) {     // clsh1 owns 3 tiles (cls 64..111)
                    int cls = (clsh * 4 + ct) * 16 + lr;
                    int swc = (cls & 7) << 4;
                    int bo = nh * 64 + g * 16;
                    short8 lhi = *(const short8*)(Lt + cls * 256 + (bo ^ swc));
                    short8 llo = *(const short8*)(Lt + cls * 256 + ((128 + bo) ^ swc));
                    #pragma unroll
                    for (int ms = 0; ms < 2; ++ms) {
                        o[ms][ct] = __builtin_amdgcn_mfma_f32_16x16x32_bf16(phi[ms], lhi, o[ms][ct], 0, 0, 0);
                        o[ms][ct] = __builtin_amdgcn_mfma_f32_16x16x32_bf16(phi[ms], llo, o[ms][ct], 0, 0, 0);
                        o[ms][ct] = __builtin_amdgcn_mfma_f32_16x16x32_bf16(plo[ms], lhi, o[ms][ct], 0, 0, 0);
                    }
                }
            }
        }
    }

    // ---- epilogue: reduce nh partials, normalize, store ----
    __syncthreads();
    float* red = (float*)&sK[0][0];            // 32 KB scratch, sK dead now
    const int role = mh * 2 + clsh;            // shared by the nh pair
    if (nh == 1) {
        #pragma unroll
        for (int ms = 0; ms < 2; ++ms)
            #pragma unroll
            for (int ct = 0; ct < 4; ++ct)
                #pragma unroll
                for (int reg = 0; reg < 4; ++reg)
                    red[((role * 32) + (ms * 4 + ct) * 4 + reg) * 64 + lane] = o[ms][ct][reg];
    }
    __syncthreads();
    if (nh == 0) {
        #pragma unroll
        for (int ms = 0; ms < 2; ++ms)
            #pragma unroll
            for (int ct = 0; ct < 4; ++ct)
                #pragma unroll
                for (int reg = 0; reg < 4; ++reg)
                    o[ms][ct][reg] += red[((role * 32) + (ms * 4 + ct) * 4 + reg) * 64 + lane];
        if (clsh == 1 && lr == 4) {            // cls 100 = (4+2)*16+4 -> denominator
            #pragma unroll
            for (int ms = 0; ms < 2; ++ms)
                #pragma unroll
                for (int reg = 0; reg < 4; ++reg)
                    sInv[mh * 32 + ms * 16 + g * 4 + reg] = 1.0f / o[ms][2][reg];
        }
    }
    __syncthreads();
    if (nh == 0) {
        #pragma unroll
        for (int ms = 0; ms < 2; ++ms) {
            #pragma unroll
            for (int ct = 0; ct < 4; ++ct) {
                if (clsh == 0 || ct < 3) {
                    int cls = (clsh * 4 + ct) * 16 + lr;
                    if (cls < C) {
                        #pragma unroll
                        for (int reg = 0; reg < 4; ++reg) {
                            int q0 = mh * 32 + ms * 16 + g * 4 + reg;
                            out[OFF_OUTLB + (size_t)(r0 + q0) * C + cls] =
                                o[ms][ct][reg] * sInv[q0];
                        }
                    }
                }
            }
        }
    }
}

// ---------------------------------------------------------------------------
__global__ void argmax_after(const float* __restrict__ LA, int* __restrict__ predA)
{
    const int lane = threadIdx.x & 63;
    const int row  = blockIdx.x * 4 + (threadIdx.x >> 6);
    float bv = LA[row * C + lane]; int bi = lane;
    const int c1 = lane + 64;
    if (c1 < C) { float v1 = LA[row * C + c1]; if (v1 > bv) { bv = v1; bi = c1; } }
    #pragma unroll
    for (int m = 32; m; m >>= 1) {
        float ov = __shfl_xor(bv, m);
        int   oi = __shfl_xor(bi, m);
        if (ov > bv || (ov == bv && oi < bi)) { bv = ov; bi = oi; }
    }
    if (lane == 0) predA[row] = bi;
}

// ---------------------------------------------------------------------------
__global__ void finalize(const int* __restrict__ predA, const int* __restrict__ predB,
                         float* __restrict__ out)
{
    __shared__ int sm[256];
    const int t = threadIdx.x;
    int local = N_TOT;
    for (int r = t; r < N_TOT; r += 256)
        if (predA[r] != predB[r] && r < local) local = r;
    sm[t] = local;
    __syncthreads();
    for (int s = 128; s; s >>= 1) {
        if (t < s) sm[t] = min(sm[t], sm[t + s]);
        __syncthreads();
    }
    if (t == 0) {
        int first = (sm[0] == N_TOT) ? 0 : sm[0];
        out[OFF_SCAL + 0] = (float)first;
        out[OFF_SCAL + 1] = (float)first;
        out[OFF_SCAL + 2] = (float)predB[first];
        out[OFF_SCAL + 3] = (float)predA[first];
        out[OFF_SCAL + 4] = (float)predB[first];
        out[OFF_SCAL + 5] = (float)predA[first];
    }
}

// ---------------------------------------------------------------------------
extern "C" void kernel_launch(void* const* d_in, const int* in_sizes, int n_in,
                              void* d_out, int out_size, void* d_ws, size_t ws_size,
                              hipStream_t stream)
{
    const float* anchor   = (const float*)d_in[0];
    const float* positive = (const float*)d_in[1];
    const float* lbf      = (const float*)d_in[2];
    const float* oh       = (const float*)d_in[3];
    const float* l_lb     = (const float*)d_in[4];
    const float* l_u1     = (const float*)d_in[5];
    const float* l_u2     = (const float*)d_in[6];
    float* out = (float*)d_out;

    u16* F2 = (u16*)d_ws;                            // 8 MB
    u16* LT = F2 + (size_t)N_TOT * 256;              // 6.8 MB
    int* predB = (int*)(LT + (size_t)2 * CT * N_TOT);
    int* predA = predB + N_TOT;

    prep_feats <<<N_TOT, 64, 0, stream>>>(anchor, positive, lbf, F2, out);
    prep_logits<<<N_TOT, 64, 0, stream>>>(l_lb, l_u1, l_u2, LT, predB);
    copy_oh    <<<200, 256, 0, stream>>>((const float4*)oh, (float4*)&out[OFF_OH]);
    attn_mfma  <<<256, 512, 0, stream>>>(F2, LT, out);
    argmax_after<<<N_TOT / 4, 256, 0, stream>>>(&out[OFF_OUTLB], predA);
    finalize   <<<1, 256, 0, stream>>>(predA, predB, out);
}

// Round 9
// 437.534 us; speedup vs baseline: 6.5874x; 1.2370x over previous
//
#include <hip/hip_runtime.h>
#include <hip/hip_bf16.h>

typedef unsigned short u16;
typedef unsigned int u32;
typedef __attribute__((ext_vector_type(8))) short short8;
typedef __attribute__((ext_vector_type(4))) short bs4;    // 4 x bf16
typedef __attribute__((ext_vector_type(4))) float f32x4;

#define N_LB   4096
#define N_ULB  6144
#define N_TOT  16384
#define D      128
#define C      100
#define CT     104   // classes stored in LT (100 logits + denom@100 + 3 zero)

// d_out element offsets (f32 elements, reference return order)
#define OFF_ANCHOR 0
#define OFF_POS    786432
#define OFF_LBF    1572864
#define OFF_OH     2097152
#define OFF_OUTLB  2506752   // out_lb / out_ulb_1 / out_ulb_2 row-contiguous
#define OFF_SCAL   4145152

__device__ __forceinline__ void split_bf16(float x, u16& hi, u16& lo) {
    __hip_bfloat16 h = __float2bfloat16(x);
    float r = x - __bfloat162float(h);
    __hip_bfloat16 l = __float2bfloat16(r);
    hi = __bfloat16_as_ushort(h);
    lo = __bfloat16_as_ushort(l);
}

// async global->LDS DMA, 16B per lane (wave-uniform LDS base + lane*16)
__device__ __forceinline__ void gl_lds16(const char* g, char* l) {
    __builtin_amdgcn_global_load_lds(
        (const __attribute__((address_space(1))) u32*)g,
        (__attribute__((address_space(3))) u32*)l, 16, 0, 0);
}

// v_mfma_f32_16x16x16_bf16: A,B = 4 bf16 (2 VGPRs), C/D = 4 f32.
// A: row=lane&15, k=(lane>>4)*4+i ; B: col=lane&15, same k ;
// D: col=lane&15, row=(lane>>4)*4+reg.
// Use the builtin so the compiler inserts the VALU-write->MFMA-read hazard
// nops (inline asm bypasses GCNHazardRecognizer -> stale-VGPR NaNs, round 8).
#if __has_builtin(__builtin_amdgcn_mfma_f32_16x16x16bf16_1k)
__device__ __forceinline__ f32x4 mfma16(bs4 a, bs4 b, f32x4 c) {
    return __builtin_amdgcn_mfma_f32_16x16x16bf16_1k(a, b, c, 0, 0, 0);
}
#else
__device__ __forceinline__ f32x4 mfma16(bs4 a, bs4 b, f32x4 c) {
    asm volatile("s_nop 4\n\tv_mfma_f32_16x16x16_bf16 %0, %1, %2, %0"
                 : "+v"(c) : "v"(a), "v"(b));
    return c;
}
#endif

// ---------------------------------------------------------------------------
// prep_feats: L2-normalize rows; split to bf16 hi/lo planes in ws
// F2[16384][256] u16 (row = [hi 0..127 | lo 128..255]); exact f32 passthrough.
// ---------------------------------------------------------------------------
__global__ void prep_feats(const float* __restrict__ anchor,
                           const float* __restrict__ positive,
                           const float* __restrict__ lbf,
                           u16* __restrict__ F2,
                           float* __restrict__ out)
{
    const int r = blockIdx.x;
    const int t = threadIdx.x;   // 0..63
    const float* src; int rr, ptbase;
    if (r < N_LB)              { src = lbf;      rr = r;                ptbase = OFF_LBF; }
    else if (r < N_LB + N_ULB) { src = anchor;   rr = r - N_LB;         ptbase = OFF_ANCHOR; }
    else                       { src = positive; rr = r - N_LB - N_ULB; ptbase = OFF_POS; }
    float2 x = *(const float2*)&src[rr * D + 2 * t];
    float ss = x.x * x.x + x.y * x.y;
    #pragma unroll
    for (int m = 32; m; m >>= 1) ss += __shfl_xor(ss, m);
    float inv = 1.0f / fmaxf(sqrtf(ss), 1e-12f);
    float y0 = x.x * inv, y1 = x.y * inv;
    u16 h0, l0, h1, l1;
    split_bf16(y0, h0, l0);
    split_bf16(y1, h1, l1);
    *(u32*)&F2[r * 256 + 2 * t]       = (u32)h0 | ((u32)h1 << 16);
    *(u32*)&F2[r * 256 + 128 + 2 * t] = (u32)l0 | ((u32)l1 << 16);
    *(float2*)&out[ptbase + rr * D + 2 * t] = x;   // exact bit copy
}

// ---------------------------------------------------------------------------
// prep_logits: transposed split-bf16 LT[pl][cls][key]; cls 100 = 1.0 (folded
// softmax denominator). pred_before via exact first-occurrence argmax.
// ---------------------------------------------------------------------------
__global__ void prep_logits(const float* __restrict__ l_lb,
                            const float* __restrict__ l_u1,
                            const float* __restrict__ l_u2,
                            u16* __restrict__ LT,
                            int* __restrict__ predB)
{
    const int r = blockIdx.x;
    const int t = threadIdx.x;   // 0..63
    const float* src; int rr;
    if (r < N_LB)              { src = l_lb; rr = r; }
    else if (r < N_LB + N_ULB) { src = l_u1; rr = r - N_LB; }
    else                       { src = l_u2; rr = r - N_LB - N_ULB; }
    float v0 = src[rr * C + t];
    const int c1 = t + 64;
    float v1 = (c1 < C) ? src[rr * C + c1] : 0.0f;
    u16 h, l;
    split_bf16(v0, h, l);
    LT[(size_t)(0 * CT + t) * N_TOT + r] = h;
    LT[(size_t)(1 * CT + t) * N_TOT + r] = l;
    if (c1 < CT) {
        float v = (c1 < C) ? v1 : ((c1 == C) ? 1.0f : 0.0f);
        split_bf16(v, h, l);
        LT[(size_t)(0 * CT + c1) * N_TOT + r] = h;
        LT[(size_t)(1 * CT + c1) * N_TOT + r] = l;
    }
    float bv = v0; int bi = t;
    if (c1 < C && v1 > bv) { bv = v1; bi = c1; }
    #pragma unroll
    for (int m = 32; m; m >>= 1) {
        float ov = __shfl_xor(bv, m);
        int   oi = __shfl_xor(bi, m);
        if (ov > bv || (ov == bv && oi < bi)) { bv = ov; bi = oi; }
    }
    if (t == 0) predB[r] = bi;
}

// ---------------------------------------------------------------------------
__global__ void copy_oh(const float4* __restrict__ oh, float4* __restrict__ out)
{
    for (int i = blockIdx.x * blockDim.x + threadIdx.x; i < N_LB * C / 4;
         i += gridDim.x * blockDim.x)
        out[i] = oh[i];
}

// ---------------------------------------------------------------------------
// attn_mfma round 9: swapped-operand S (A=K, B=Q) so each lane's S output
// (q = lane&15, keys = g*4+reg) IS the 16x16x16 PV A-fragment -> P stays in
// registers: no sP buffer, no mid-chunk barrier. ONE __syncthreads per chunk
// (its vmcnt(0) is the DMA(ch) deadline; DMA(ch+1) issued right after).
// Waves: (mh in 2) x (nq in 4): S = 16 keys x 32 q (2 ms tiles, 24 x32-MFMA);
// PV = 32 q x 112 cls x 16 keys (42 x16-MFMA). Epilogue: 4-way nq reduction.
// ---------------------------------------------------------------------------
#define SK_BYTES  (64 * 512)     // key tile: 64 rows x [hi 256B | lo 256B]
#define SLT_BYTES (112 * 256)    // L^T tile: 112 cls x [hi 128B | lo 128B]

__launch_bounds__(512)
__global__ void attn_mfma(const u16* __restrict__ F2, const u16* __restrict__ LT,
                          float* __restrict__ out)
{
    // manual partition: [sK0|sK1|sLT0|sLT1|sInv]; epilogue reuses front 86KB
    __shared__ __align__(16) char smem[2 * SK_BYTES + 2 * SLT_BYTES + 256];
    char* const sK0  = smem;
    char* const sK1  = smem + SK_BYTES;
    char* const sLT0 = smem + 2 * SK_BYTES;
    char* const sLT1 = smem + 2 * SK_BYTES + SLT_BYTES;
    float* const sInv = (float*)(smem + 2 * SK_BYTES + 2 * SLT_BYTES);

    const int tid  = threadIdx.x;
    const int lane = tid & 63;
    const int w    = tid >> 6;      // 0..7
    const int mh   = w >> 2;        // 32-q half
    const int nq   = w & 3;         // 16-key column
    const int g    = lane >> 4;     // k-group
    const int lr   = lane & 15;
    const int r0   = blockIdx.x * 64;

    const char* F2b = (const char*)F2;
    const char* LTb = (const char*)LT;

    // zero-fill sLT class rows 104..111 (both buffers) once; never restaged
    if (tid < 256) {
        char* dst = (tid >> 7) ? sLT1 : sLT0;
        int row = 104 + ((tid & 127) >> 4), gr = tid & 15;
        *(f32x4*)(dst + row * 256 + gr * 16) = f32x4{0, 0, 0, 0};
    }

    // Q fragments (registers, hi/lo) for both 16-q subtiles of this mh-half
    short8 qhi[2][4], qlo[2][4];
    #pragma unroll
    for (int ms = 0; ms < 2; ++ms) {
        const char* base = F2b + (size_t)(r0 + mh * 32 + ms * 16 + lr) * 512;
        #pragma unroll
        for (int ks = 0; ks < 4; ++ks) {
            qhi[ms][ks] = *(const short8*)(base + ks * 64 + g * 16);
            qlo[ms][ks] = *(const short8*)(base + 256 + ks * 64 + g * 16);
        }
    }

    // ---- prologue: stage chunk 0 into buffer 0 ----
    #pragma unroll
    for (int it = 0; it < 4; ++it) {
        int idx = tid + it * 512;
        int row = idx >> 5, b = (idx & 31) << 4;
        gl_lds16(F2b + (size_t)row * 512 + (b ^ ((row & 7) << 4)), sK0 + idx * 16);
    }
    #pragma unroll
    for (int it = 0; it < 4; ++it) {
        int idx = tid + it * 512;
        if (idx < 1664) {
            int row = idx >> 4, b = (idx & 15) << 4;
            int b2 = b ^ ((row & 7) << 4);
            int pl = b2 >> 7, kb = b2 & 127;
            gl_lds16(LTb + ((size_t)(pl * CT + row) * N_TOT) * 2 + kb, sLT0 + idx * 16);
        }
    }

    f32x4 o[2][7];                  // [ms][cls-tile]; lane: cls=lr, q=g*4+reg
    #pragma unroll
    for (int ms = 0; ms < 2; ++ms)
        #pragma unroll
        for (int ct = 0; ct < 7; ++ct) o[ms][ct] = f32x4{0, 0, 0, 0};

    for (int ch = 0; ch < 256; ++ch) {
        const int cur = ch & 1;
        __syncthreads();   // drains own DMA (vmcnt 0): tile(ch) ready; other buf free

        // ---- issue async staging for chunk ch+1 ----
        if (ch + 1 < 256) {
            const int cn = (ch + 1) * 64;
            char* dK = cur ? sK0 : sK1;
            char* dL = cur ? sLT0 : sLT1;
            #pragma unroll
            for (int it = 0; it < 4; ++it) {
                int idx = tid + it * 512;
                int row = idx >> 5, b = (idx & 31) << 4;
                gl_lds16(F2b + (size_t)(cn + row) * 512 + (b ^ ((row & 7) << 4)),
                         dK + idx * 16);
            }
            #pragma unroll
            for (int it = 0; it < 4; ++it) {
                int idx = tid + it * 512;
                if (idx < 1664) {
                    int row = idx >> 4, b = (idx & 15) << 4;
                    int b2 = b ^ ((row & 7) << 4);
                    int pl = b2 >> 7, kb = b2 & 127;
                    gl_lds16(LTb + ((size_t)(pl * CT + row) * N_TOT + cn) * 2 + kb,
                             dL + idx * 16);
                }
            }
        }

        // ---- S = K.Q^T (swapped): acc[key=g*4+reg][q=lr], per ms ----
        const char* K = cur ? sK1 : sK0;
        const int krow = nq * 16 + lr;
        const int sw = (krow & 7) << 4;
        short8 khi[4], klo[4];
        #pragma unroll
        for (int ks = 0; ks < 4; ++ks) {
            int bo = ks * 64 + g * 16;
            khi[ks] = *(const short8*)(K + krow * 512 + (bo ^ sw));
            klo[ks] = *(const short8*)(K + krow * 512 + ((256 + bo) ^ sw));
        }
        bs4 pa_hi[2], pa_lo[2];
        #pragma unroll
        for (int ms = 0; ms < 2; ++ms) {
            f32x4 acc = {0, 0, 0, 0};
            #pragma unroll
            for (int ks = 0; ks < 4; ++ks)
                acc = __builtin_amdgcn_mfma_f32_16x16x32_bf16(khi[ks], qhi[ms][ks], acc, 0, 0, 0);
            #pragma unroll
            for (int ks = 0; ks < 4; ++ks)
                acc = __builtin_amdgcn_mfma_f32_16x16x32_bf16(khi[ks], qlo[ms][ks], acc, 0, 0, 0);
            #pragma unroll
            for (int ks = 0; ks < 4; ++ks)
                acc = __builtin_amdgcn_mfma_f32_16x16x32_bf16(klo[ks], qhi[ms][ks], acc, 0, 0, 0);
            u16 h[4], l[4];
            #pragma unroll
            for (int reg = 0; reg < 4; ++reg) {
                float p = __expf(10.0f * acc[reg] - 10.0f);
                split_bf16(p, h[reg], l[reg]);
            }
            pa_hi[ms] = bs4{(short)h[0], (short)h[1], (short)h[2], (short)h[3]};
            pa_lo[ms] = bs4{(short)l[0], (short)l[1], (short)l[2], (short)l[3]};
        }

        // ---- PV: o[q 32][cls 112] += P(16 keys) . L^T, K=16 MFMAs ----
        const char* Lt = cur ? sLT1 : sLT0;
        #pragma unroll
        for (int ct = 0; ct < 7; ++ct) {
            int cls = ct * 16 + lr;
            int swc = (cls & 7) << 4;
            int boh = (nq * 32 + g * 8) ^ swc;          // hi plane, 8B granule
            int bol = (128 + nq * 32 + g * 8) ^ swc;    // lo plane
            bs4 lhi = *(const bs4*)(Lt + cls * 256 + boh);
            bs4 llo = *(const bs4*)(Lt + cls * 256 + bol);
            #pragma unroll
            for (int ms = 0; ms < 2; ++ms) {
                o[ms][ct] = mfma16(pa_hi[ms], lhi, o[ms][ct]);
                o[ms][ct] = mfma16(pa_hi[ms], llo, o[ms][ct]);
                o[ms][ct] = mfma16(pa_lo[ms], lhi, o[ms][ct]);
            }
        }
    }

    // ---- epilogue: 4-way nq reduction, normalize, store ----
    __syncthreads();
    float* red = (float*)smem;      // 86016 B scratch (sK + part of sLT0), dead now
    if (nq != 0) {
        #pragma unroll
        for (int ms = 0; ms < 2; ++ms)
            #pragma unroll
            for (int ct = 0; ct < 7; ++ct)
                #pragma unroll
                for (int reg = 0; reg < 4; ++reg)
                    red[((((nq - 1) * 2 + mh) * 14) + ms * 7 + ct) * 256 + reg * 64 + lane]
                        = o[ms][ct][reg];
    }
    __syncthreads();
    if (nq == 0) {
        #pragma unroll
        for (int j = 0; j < 3; ++j)
            #pragma unroll
            for (int ms = 0; ms < 2; ++ms)
                #pragma unroll
                for (int ct = 0; ct < 7; ++ct)
                    #pragma unroll
                    for (int reg = 0; reg < 4; ++reg)
                        o[ms][ct][reg] +=
                            red[(((j * 2 + mh) * 14) + ms * 7 + ct) * 256 + reg * 64 + lane];
        if (lr == 4) {              // cls 100 = ct 6, lr 4 -> denominator
            #pragma unroll
            for (int ms = 0; ms < 2; ++ms)
                #pragma unroll
                for (int reg = 0; reg < 4; ++reg)
                    sInv[mh * 32 + ms * 16 + g * 4 + reg] = 1.0f / o[ms][6][reg];
        }
    }
    __syncthreads();
    if (nq == 0) {
        #pragma unroll
        for (int ms = 0; ms < 2; ++ms) {
            #pragma unroll
            for (int ct = 0; ct < 7; ++ct) {
                int cls = ct * 16 + lr;
                if (cls < C) {
                    #pragma unroll
                    for (int reg = 0; reg < 4; ++reg) {
                        int q = mh * 32 + ms * 16 + g * 4 + reg;
                        out[OFF_OUTLB + (size_t)(r0 + q) * C + cls] =
                            o[ms][ct][reg] * sInv[q];
                    }
                }
            }
        }
    }
}

// ---------------------------------------------------------------------------
__global__ void argmax_after(const float* __restrict__ LA, int* __restrict__ predA)
{
    const int lane = threadIdx.x & 63;
    const int row  = blockIdx.x * 4 + (threadIdx.x >> 6);
    float bv = LA[row * C + lane]; int bi = lane;
    const int c1 = lane + 64;
    if (c1 < C) { float v1 = LA[row * C + c1]; if (v1 > bv) { bv = v1; bi = c1; } }
    #pragma unroll
    for (int m = 32; m; m >>= 1) {
        float ov = __shfl_xor(bv, m);
        int   oi = __shfl_xor(bi, m);
        if (ov > bv || (ov == bv && oi < bi)) { bv = ov; bi = oi; }
    }
    if (lane == 0) predA[row] = bi;
}

// ---------------------------------------------------------------------------
__global__ void finalize(const int* __restrict__ predA, const int* __restrict__ predB,
                         float* __restrict__ out)
{
    __shared__ int sm[256];
    const int t = threadIdx.x;
    int local = N_TOT;
    for (int r = t; r < N_TOT; r += 256)
        if (predA[r] != predB[r] && r < local) local = r;
    sm[t] = local;
    __syncthreads();
    for (int s = 128; s; s >>= 1) {
        if (t < s) sm[t] = min(sm[t], sm[t + s]);
        __syncthreads();
    }
    if (t == 0) {
        int first = (sm[0] == N_TOT) ? 0 : sm[0];
        out[OFF_SCAL + 0] = (float)first;
        out[OFF_SCAL + 1] = (float)first;
        out[OFF_SCAL + 2] = (float)predB[first];
        out[OFF_SCAL + 3] = (float)predA[first];
        out[OFF_SCAL + 4] = (float)predB[first];
        out[OFF_SCAL + 5] = (float)predA[first];
    }
}

// ---------------------------------------------------------------------------
extern "C" void kernel_launch(void* const* d_in, const int* in_sizes, int n_in,
                              void* d_out, int out_size, void* d_ws, size_t ws_size,
                              hipStream_t stream)
{
    const float* anchor   = (const float*)d_in[0];
    const float* positive = (const float*)d_in[1];
    const float* lbf      = (const float*)d_in[2];
    const float* oh       = (const float*)d_in[3];
    const float* l_lb     = (const float*)d_in[4];
    const float* l_u1     = (const float*)d_in[5];
    const float* l_u2     = (const float*)d_in[6];
    float* out = (float*)d_out;

    u16* F2 = (u16*)d_ws;                            // 8 MB
    u16* LT = F2 + (size_t)N_TOT * 256;              // 6.8 MB
    int* predB = (int*)(LT + (size_t)2 * CT * N_TOT);
    int* predA = predB + N_TOT;

    prep_feats <<<N_TOT, 64, 0, stream>>>(anchor, positive, lbf, F2, out);
    prep_logits<<<N_TOT, 64, 0, stream>>>(l_lb, l_u1, l_u2, LT, predB);
    copy_oh    <<<200, 256, 0, stream>>>((const float4*)oh, (float4*)&out[OFF_OH]);
    attn_mfma  <<<256, 512, 0, stream>>>(F2, LT, out);
    argmax_after<<<N_TOT / 4, 256, 0, stream>>>(&out[OFF_OUTLB], predA);
    finalize   <<<1, 256, 0, stream>>>(predA, predB, out);
}

// Round 10
// 417.652 us; speedup vs baseline: 6.9010x; 1.0476x over previous
//
#include <hip/hip_runtime.h>
#include <hip/hip_bf16.h>

typedef unsigned short u16;
typedef unsigned int u32;
typedef __attribute__((ext_vector_type(8))) short short8;
typedef __attribute__((ext_vector_type(4))) float f32x4;

#define N_LB   4096
#define N_ULB  6144
#define N_TOT  16384
#define D      128
#define C      100
#define CT     104   // classes stored in LT (100 logits + denom@100 + 3 zero)

// d_out element offsets (f32 elements, reference return order)
#define OFF_ANCHOR 0
#define OFF_POS    786432
#define OFF_LBF    1572864
#define OFF_OH     2097152
#define OFF_OUTLB  2506752   // out_lb / out_ulb_1 / out_ulb_2 row-contiguous
#define OFF_SCAL   4145152

__device__ __forceinline__ void split_bf16(float x, u16& hi, u16& lo) {
    __hip_bfloat16 h = __float2bfloat16(x);
    float r = x - __bfloat162float(h);
    __hip_bfloat16 l = __float2bfloat16(r);
    hi = __bfloat16_as_ushort(h);
    lo = __bfloat16_as_ushort(l);
}

// async global->LDS DMA, 16B per lane (wave-uniform LDS base + lane*16)
__device__ __forceinline__ void gl_lds16(const char* g, char* l) {
    __builtin_amdgcn_global_load_lds(
        (const __attribute__((address_space(1))) u32*)g,
        (__attribute__((address_space(3))) u32*)l, 16, 0, 0);
}

// ---------------------------------------------------------------------------
// prep_feats: L2-normalize rows; split to bf16 hi/lo planes in ws
// F2[16384][256] u16 (row = [hi 0..127 | lo 128..255]); exact f32 passthrough.
// ---------------------------------------------------------------------------
__global__ void prep_feats(const float* __restrict__ anchor,
                           const float* __restrict__ positive,
                           const float* __restrict__ lbf,
                           u16* __restrict__ F2,
                           float* __restrict__ out)
{
    const int r = blockIdx.x;
    const int t = threadIdx.x;   // 0..63
    const float* src; int rr, ptbase;
    if (r < N_LB)              { src = lbf;      rr = r;                ptbase = OFF_LBF; }
    else if (r < N_LB + N_ULB) { src = anchor;   rr = r - N_LB;         ptbase = OFF_ANCHOR; }
    else                       { src = positive; rr = r - N_LB - N_ULB; ptbase = OFF_POS; }
    float2 x = *(const float2*)&src[rr * D + 2 * t];
    float ss = x.x * x.x + x.y * x.y;
    #pragma unroll
    for (int m = 32; m; m >>= 1) ss += __shfl_xor(ss, m);
    float inv = 1.0f / fmaxf(sqrtf(ss), 1e-12f);
    float y0 = x.x * inv, y1 = x.y * inv;
    u16 h0, l0, h1, l1;
    split_bf16(y0, h0, l0);
    split_bf16(y1, h1, l1);
    *(u32*)&F2[r * 256 + 2 * t]       = (u32)h0 | ((u32)h1 << 16);
    *(u32*)&F2[r * 256 + 128 + 2 * t] = (u32)l0 | ((u32)l1 << 16);
    *(float2*)&out[ptbase + rr * D + 2 * t] = x;   // exact bit copy
}

// ---------------------------------------------------------------------------
// prep_logits: transposed split-bf16 LT[pl][cls][key_permuted]; cls 100 = 1.0
// (folded softmax denominator). KEY PERMUTATION: within each 32-key window,
// logical key kl = t*16 + g*4 + r is stored at column j = g*8 + r*2 + t so a
// wave's in-register P (lane g holds keys {t*16+g*4+r}) matches the
// 16x16x32 A-fragment slot order (k = g*8 + i) -> PV runs K=32 MFMAs with a
// plain contiguous 16B B-read. pred_before via exact first-occurrence argmax.
// ---------------------------------------------------------------------------
__global__ void prep_logits(const float* __restrict__ l_lb,
                            const float* __restrict__ l_u1,
                            const float* __restrict__ l_u2,
                            u16* __restrict__ LT,
                            int* __restrict__ predB)
{
    const int r = blockIdx.x;
    const int t = threadIdx.x;   // 0..63
    const float* src; int rr;
    if (r < N_LB)              { src = l_lb; rr = r; }
    else if (r < N_LB + N_ULB) { src = l_u1; rr = r - N_LB; }
    else                       { src = l_u2; rr = r - N_LB - N_ULB; }
    // permuted storage column for key r
    const int pc = (r & ~31) | (((r >> 2) & 3) << 3) | ((r & 3) << 1) | ((r >> 4) & 1);
    float v0 = src[rr * C + t];
    const int c1 = t + 64;
    float v1 = (c1 < C) ? src[rr * C + c1] : 0.0f;
    u16 h, l;
    split_bf16(v0, h, l);
    LT[(size_t)(0 * CT + t) * N_TOT + pc] = h;
    LT[(size_t)(1 * CT + t) * N_TOT + pc] = l;
    if (c1 < CT) {
        float v = (c1 < C) ? v1 : ((c1 == C) ? 1.0f : 0.0f);
        split_bf16(v, h, l);
        LT[(size_t)(0 * CT + c1) * N_TOT + pc] = h;
        LT[(size_t)(1 * CT + c1) * N_TOT + pc] = l;
    }
    float bv = v0; int bi = t;
    if (c1 < C && v1 > bv) { bv = v1; bi = c1; }
    #pragma unroll
    for (int m = 32; m; m >>= 1) {
        float ov = __shfl_xor(bv, m);
        int   oi = __shfl_xor(bi, m);
        if (ov > bv || (ov == bv && oi < bi)) { bv = ov; bi = oi; }
    }
    if (t == 0) predB[r] = bi;
}

// ---------------------------------------------------------------------------
__global__ void copy_oh(const float4* __restrict__ oh, float4* __restrict__ out)
{
    for (int i = blockIdx.x * blockDim.x + threadIdx.x; i < N_LB * C / 4;
         i += gridDim.x * blockDim.x)
        out[i] = oh[i];
}

// ---------------------------------------------------------------------------
// attn_mfma round 10: all-x32 pipeline. Waves = (m in 4 q-tiles) x (nqh in 2
// 32-key windows). S (swapped A=K,B=Q) over 2 ktiles -> lane holds P[q=lr] for
// keys {t*16+g*4+r}; exp+split packs DIRECTLY into the K=32 PV A-fragment
// (slot i=2r+t), whose key order matches LT's permuted columns. PV = 21 x32
// per wave (was 42 x16: same FLOP, half the issue slots). One barrier/chunk;
// double-buffered DMA staging; sK swizzle widened to (row&15)<<4.
// ---------------------------------------------------------------------------
#define SK_BYTES  (64 * 512)     // key tile: 64 rows x [hi 256B | lo 256B]
#define SLT_BYTES (112 * 256)    // L^T tile: 112 cls x [hi 128B | lo 128B]

__launch_bounds__(512)
__global__ void attn_mfma(const u16* __restrict__ F2, const u16* __restrict__ LT,
                          float* __restrict__ out)
{
    // manual partition: [sK0|sK1|sLT0|sLT1|sInv]; epilogue reuses front 28KB
    __shared__ __align__(16) char smem[2 * SK_BYTES + 2 * SLT_BYTES + 256];
    char* const sK0  = smem;
    char* const sK1  = smem + SK_BYTES;
    char* const sLT0 = smem + 2 * SK_BYTES;
    char* const sLT1 = smem + 2 * SK_BYTES + SLT_BYTES;
    float* const sInv = (float*)(smem + 2 * SK_BYTES + 2 * SLT_BYTES);

    const int tid  = threadIdx.x;
    const int lane = tid & 63;
    const int w    = tid >> 6;      // 0..7
    const int m    = w >> 1;        // 16-q tile
    const int nqh  = w & 1;         // 32-key window
    const int g    = lane >> 4;     // k-group
    const int lr   = lane & 15;
    const int r0   = blockIdx.x * 64;

    const char* F2b = (const char*)F2;
    const char* LTb = (const char*)LT;

    // zero-fill sLT class rows 104..111 (both buffers) once; never restaged
    if (tid < 256) {
        char* dst = (tid >> 7) ? sLT1 : sLT0;
        int row = 104 + ((tid & 127) >> 4), gr = tid & 15;
        *(f32x4*)(dst + row * 256 + gr * 16) = f32x4{0, 0, 0, 0};
    }

    // Q fragments (registers, hi/lo): q = r0 + m*16 + lr
    short8 qhi[4], qlo[4];
    {
        const char* base = F2b + (size_t)(r0 + m * 16 + lr) * 512;
        #pragma unroll
        for (int ks = 0; ks < 4; ++ks) {
            qhi[ks] = *(const short8*)(base + ks * 64 + g * 16);
            qlo[ks] = *(const short8*)(base + 256 + ks * 64 + g * 16);
        }
    }

    // ---- prologue: stage chunk 0 into buffer 0 ----
    #pragma unroll
    for (int it = 0; it < 4; ++it) {
        int idx = tid + it * 512;
        int row = idx >> 5, b = (idx & 31) << 4;
        gl_lds16(F2b + (size_t)row * 512 + (b ^ ((row & 15) << 4)), sK0 + idx * 16);
    }
    #pragma unroll
    for (int it = 0; it < 4; ++it) {
        int idx = tid + it * 512;
        if (idx < 1664) {
            int row = idx >> 4, b = (idx & 15) << 4;
            int b2 = b ^ ((row & 7) << 4);
            int pl = b2 >> 7, kb = b2 & 127;
            gl_lds16(LTb + ((size_t)(pl * CT + row) * N_TOT) * 2 + kb, sLT0 + idx * 16);
        }
    }

    f32x4 o[7];                     // [cls-tile]; lane: cls=lr, q=m*16+g*4+reg
    #pragma unroll
    for (int ct = 0; ct < 7; ++ct) o[ct] = f32x4{0, 0, 0, 0};

    for (int ch = 0; ch < 256; ++ch) {
        const int cur = ch & 1;
        __syncthreads();   // drains own DMA (vmcnt 0): tile(ch) ready; other buf free

        // ---- issue async staging for chunk ch+1 ----
        if (ch + 1 < 256) {
            const int cn = (ch + 1) * 64;
            char* dK = cur ? sK0 : sK1;
            char* dL = cur ? sLT0 : sLT1;
            #pragma unroll
            for (int it = 0; it < 4; ++it) {
                int idx = tid + it * 512;
                int row = idx >> 5, b = (idx & 31) << 4;
                gl_lds16(F2b + (size_t)(cn + row) * 512 + (b ^ ((row & 15) << 4)),
                         dK + idx * 16);
            }
            #pragma unroll
            for (int it = 0; it < 4; ++it) {
                int idx = tid + it * 512;
                if (idx < 1664) {
                    int row = idx >> 4, b = (idx & 15) << 4;
                    int b2 = b ^ ((row & 7) << 4);
                    int pl = b2 >> 7, kb = b2 & 127;
                    gl_lds16(LTb + ((size_t)(pl * CT + row) * N_TOT + cn) * 2 + kb,
                             dL + idx * 16);
                }
            }
        }

        // ---- S = K.Q^T over 2 ktiles: acc_t[key=g*4+reg][q=lr] ----
        const char* K = cur ? sK1 : sK0;
        u16 h[2][4], l[2][4];
        #pragma unroll
        for (int t = 0; t < 2; ++t) {
            const int krow = nqh * 32 + t * 16 + lr;
            const int sw = (krow & 15) << 4;
            short8 khi[4], klo[4];
            #pragma unroll
            for (int ks = 0; ks < 4; ++ks) {
                int bo = ks * 64 + g * 16;
                khi[ks] = *(const short8*)(K + krow * 512 + (bo ^ sw));
                klo[ks] = *(const short8*)(K + krow * 512 + ((256 + bo) ^ sw));
            }
            f32x4 acc = {0, 0, 0, 0};
            #pragma unroll
            for (int ks = 0; ks < 4; ++ks)
                acc = __builtin_amdgcn_mfma_f32_16x16x32_bf16(khi[ks], qhi[ks], acc, 0, 0, 0);
            #pragma unroll
            for (int ks = 0; ks < 4; ++ks)
                acc = __builtin_amdgcn_mfma_f32_16x16x32_bf16(khi[ks], qlo[ks], acc, 0, 0, 0);
            #pragma unroll
            for (int ks = 0; ks < 4; ++ks)
                acc = __builtin_amdgcn_mfma_f32_16x16x32_bf16(klo[ks], qhi[ks], acc, 0, 0, 0);
            #pragma unroll
            for (int reg = 0; reg < 4; ++reg) {
                float p = __expf(10.0f * acc[reg] - 10.0f);
                split_bf16(p, h[t][reg], l[t][reg]);
            }
        }
        // pack P into K=32 A-fragments: slot i = 2r + t  (matches LT's perm)
        short8 Ahi = short8{(short)h[0][0], (short)h[1][0], (short)h[0][1], (short)h[1][1],
                            (short)h[0][2], (short)h[1][2], (short)h[0][3], (short)h[1][3]};
        short8 Alo = short8{(short)l[0][0], (short)l[1][0], (short)l[0][1], (short)l[1][1],
                            (short)l[0][2], (short)l[1][2], (short)l[0][3], (short)l[1][3]};

        // ---- PV: o[q 16][cls 112] += P(32 keys) . L^T, K=32 x32-MFMAs ----
        const char* Lt = cur ? sLT1 : sLT0;
        #pragma unroll
        for (int ct = 0; ct < 7; ++ct) {
            int cls = ct * 16 + lr;
            int swc = (cls & 7) << 4;
            int boh = (nqh * 64 + g * 16) ^ swc;        // hi plane (16B granule)
            int bol = 128 + boh;                        // lo plane
            short8 Bhi = *(const short8*)(Lt + cls * 256 + boh);
            short8 Blo = *(const short8*)(Lt + cls * 256 + bol);
            o[ct] = __builtin_amdgcn_mfma_f32_16x16x32_bf16(Ahi, Bhi, o[ct], 0, 0, 0);
            o[ct] = __builtin_amdgcn_mfma_f32_16x16x32_bf16(Ahi, Blo, o[ct], 0, 0, 0);
            o[ct] = __builtin_amdgcn_mfma_f32_16x16x32_bf16(Alo, Bhi, o[ct], 0, 0, 0);
        }
    }

    // ---- epilogue: 2-way nqh reduction, normalize, store ----
    __syncthreads();
    float* red = (float*)smem;      // 28 KB scratch, tiles dead now
    if (nqh == 1) {
        #pragma unroll
        for (int ct = 0; ct < 7; ++ct)
            #pragma unroll
            for (int reg = 0; reg < 4; ++reg)
                red[(m * 7 + ct) * 256 + reg * 64 + lane] = o[ct][reg];
    }
    __syncthreads();
    if (nqh == 0) {
        #pragma unroll
        for (int ct = 0; ct < 7; ++ct)
            #pragma unroll
            for (int reg = 0; reg < 4; ++reg)
                o[ct][reg] += red[(m * 7 + ct) * 256 + reg * 64 + lane];
        if (lr == 4) {              // cls 100 = ct 6, lr 4 -> denominator
            #pragma unroll
            for (int reg = 0; reg < 4; ++reg)
                sInv[m * 16 + g * 4 + reg] = 1.0f / o[6][reg];
        }
    }
    __syncthreads();
    if (nqh == 0) {
        #pragma unroll
        for (int ct = 0; ct < 7; ++ct) {
            int cls = ct * 16 + lr;
            if (cls < C) {
                #pragma unroll
                for (int reg = 0; reg < 4; ++reg) {
                    int q = m * 16 + g * 4 + reg;
                    out[OFF_OUTLB + (size_t)(r0 + q) * C + cls] =
                        o[ct][reg] * sInv[q];
                }
            }
        }
    }
}

// ---------------------------------------------------------------------------
__global__ void argmax_after(const float* __restrict__ LA, int* __restrict__ predA)
{
    const int lane = threadIdx.x & 63;
    const int row  = blockIdx.x * 4 + (threadIdx.x >> 6);
    float bv = LA[row * C + lane]; int bi = lane;
    const int c1 = lane + 64;
    if (c1 < C) { float v1 = LA[row * C + c1]; if (v1 > bv) { bv = v1; bi = c1; } }
    #pragma unroll
    for (int m = 32; m; m >>= 1) {
        float ov = __shfl_xor(bv, m);
        int   oi = __shfl_xor(bi, m);
        if (ov > bv || (ov == bv && oi < bi)) { bv = ov; bi = oi; }
    }
    if (lane == 0) predA[row] = bi;
}

// ---------------------------------------------------------------------------
__global__ void finalize(const int* __restrict__ predA, const int* __restrict__ predB,
                         float* __restrict__ out)
{
    __shared__ int sm[256];
    const int t = threadIdx.x;
    int local = N_TOT;
    for (int r = t; r < N_TOT; r += 256)
        if (predA[r] != predB[r] && r < local) local = r;
    sm[t] = local;
    __syncthreads();
    for (int s = 128; s; s >>= 1) {
        if (t < s) sm[t] = min(sm[t], sm[t + s]);
        __syncthreads();
    }
    if (t == 0) {
        int first = (sm[0] == N_TOT) ? 0 : sm[0];
        out[OFF_SCAL + 0] = (float)first;
        out[OFF_SCAL + 1] = (float)first;
        out[OFF_SCAL + 2] = (float)predB[first];
        out[OFF_SCAL + 3] = (float)predA[first];
        out[OFF_SCAL + 4] = (float)predB[first];
        out[OFF_SCAL + 5] = (float)predA[first];
    }
}

// ---------------------------------------------------------------------------
extern "C" void kernel_launch(void* const* d_in, const int* in_sizes, int n_in,
                              void* d_out, int out_size, void* d_ws, size_t ws_size,
                              hipStream_t stream)
{
    const float* anchor   = (const float*)d_in[0];
    const float* positive = (const float*)d_in[1];
    const float* lbf      = (const float*)d_in[2];
    const float* oh       = (const float*)d_in[3];
    const float* l_lb     = (const float*)d_in[4];
    const float* l_u1     = (const float*)d_in[5];
    const float* l_u2     = (const float*)d_in[6];
    float* out = (float*)d_out;

    u16* F2 = (u16*)d_ws;                            // 8 MB
    u16* LT = F2 + (size_t)N_TOT * 256;              // 6.8 MB
    int* predB = (int*)(LT + (size_t)2 * CT * N_TOT);
    int* predA = predB + N_TOT;

    prep_feats <<<N_TOT, 64, 0, stream>>>(anchor, positive, lbf, F2, out);
    prep_logits<<<N_TOT, 64, 0, stream>>>(l_lb, l_u1, l_u2, LT, predB);
    copy_oh    <<<200, 256, 0, stream>>>((const float4*)oh, (float4*)&out[OFF_OH]);
    attn_mfma  <<<256, 512, 0, stream>>>(F2, LT, out);
    argmax_after<<<N_TOT / 4, 256, 0, stream>>>(&out[OFF_OUTLB], predA);
    finalize   <<<1, 256, 0, stream>>>(predA, predB, out);
}